// Round 1
// baseline (572.671 us; speedup 1.0000x reference)
//
#include <hip/hip_runtime.h>
#include <math.h>

#define THREADS 256

// ---------------- setup kernels ----------------

__global__ __launch_bounds__(THREADS) void init_kernel(float* deg, int* cnt, int* cursor, int n) {
  int i = blockIdx.x * THREADS + threadIdx.x;
  if (i < n) { deg[i] = 1.0f; cnt[i] = 0; cursor[i] = 0; }
}

__global__ __launch_bounds__(THREADS) void edge_deg_kernel(const int* __restrict__ ei, const float* __restrict__ ew,
                                                           float* __restrict__ deg, int* __restrict__ cnt, int E) {
  int e = blockIdx.x * THREADS + threadIdx.x;
  if (e >= E) return;
  int d = ei[E + e];
  atomicAdd(deg + d, ew[e]);
  atomicAdd(cnt + d, 1);
}

__global__ __launch_bounds__(THREADS) void dinv_kernel(float* deg, int n) {
  int i = blockIdx.x * THREADS + threadIdx.x;
  if (i < n) deg[i] = rsqrtf(deg[i]);   // deg >= 1 always (self loop)
}

__global__ __launch_bounds__(1024) void scan_kernel(const int* __restrict__ cnt, int* __restrict__ rstart, int n) {
  __shared__ int sums[1024];
  int t = threadIdx.x;
  int chunk = (n + 1023) >> 10;
  int b = t * chunk;
  int e = min(b + chunk, n);
  int s = 0;
  for (int i = b; i < e; i++) s += cnt[i];
  sums[t] = s;
  __syncthreads();
  for (int off = 1; off < 1024; off <<= 1) {
    int v = (t >= off) ? sums[t - off] : 0;
    __syncthreads();
    sums[t] += v;
    __syncthreads();
  }
  int run = (t > 0) ? sums[t - 1] : 0;
  for (int i = b; i < e; i++) { rstart[i] = run; run += cnt[i]; }
}

__global__ __launch_bounds__(THREADS) void csr_fill_kernel(const int* __restrict__ ei, const float* __restrict__ ew,
                                                           const float* __restrict__ dinv,
                                                           const int* __restrict__ rstart, int* __restrict__ cursor,
                                                           int* __restrict__ csr_src, float* __restrict__ csr_norm, int E) {
  int e = blockIdx.x * THREADS + threadIdx.x;
  if (e >= E) return;
  int s = ei[e];
  int d = ei[E + e];
  int pos = rstart[d] + atomicAdd(cursor + d, 1);
  csr_src[pos] = s;
  csr_norm[pos] = dinv[s] * ew[e] * dinv[d];
}

// ---------------- GEMM: C[M,N] = A[M,128] @ W[128,N] (+bias) ----------------

#define GBM 64
#define GBN 64
#define GK 128

__global__ __launch_bounds__(256) void gemm_k128(const float* __restrict__ A, const float* __restrict__ W,
                                                 const float* __restrict__ bias, float* __restrict__ C,
                                                 int M, int N) {
  __shared__ float As[GK][GBM];   // A tile transposed: As[k][m]
  __shared__ float Ws[GK][GBN];   // Ws[k][n]
  int tid = threadIdx.x;
  int bm = blockIdx.x * GBM;
  int bn = blockIdx.y * GBN;

  {   // load A tile
    int r = tid >> 2;          // 0..63
    int cq = tid & 3;          // 0..3
    int row = bm + r;
    const float* Ap = A + (size_t)row * GK;
    bool ok = row < M;
#pragma unroll
    for (int j = 0; j < 8; j++) {
      int c = 4 * (cq + 4 * j);
      float4 v = make_float4(0.f, 0.f, 0.f, 0.f);
      if (ok) v = *(const float4*)(Ap + c);
      As[c + 0][r] = v.x; As[c + 1][r] = v.y; As[c + 2][r] = v.z; As[c + 3][r] = v.w;
    }
  }
  {   // load W tile
    int jq = tid & 15;
    int k0 = tid >> 4;         // 0..15
#pragma unroll
    for (int j = 0; j < 8; j++) {
      int k = k0 + 16 * j;
      float4 v = *(const float4*)(W + (size_t)k * N + bn + 4 * jq);
      *(float4*)(&Ws[k][4 * jq]) = v;
    }
  }
  __syncthreads();

  int tx = tid & 15, ty = tid >> 4;
  float acc[4][4] = {};
#pragma unroll 4
  for (int k = 0; k < GK; k++) {
    float4 a = *(const float4*)(&As[k][4 * ty]);
    float4 w = *(const float4*)(&Ws[k][4 * tx]);
    float av[4] = {a.x, a.y, a.z, a.w};
    float wv[4] = {w.x, w.y, w.z, w.w};
#pragma unroll
    for (int i = 0; i < 4; i++)
#pragma unroll
      for (int jj = 0; jj < 4; jj++)
        acc[i][jj] += av[i] * wv[jj];
  }

  float4 bv = make_float4(0.f, 0.f, 0.f, 0.f);
  if (bias) bv = *(const float4*)(bias + bn + 4 * tx);
#pragma unroll
  for (int i = 0; i < 4; i++) {
    int row = bm + 4 * ty + i;
    if (row < M) {
      float4 o;
      o.x = acc[i][0] + bv.x;
      o.y = acc[i][1] + bv.y;
      o.z = acc[i][2] + bv.z;
      o.w = acc[i][3] + bv.w;
      *(float4*)(C + (size_t)row * N + bn + 4 * tx) = o;
    }
  }
}

// ---------------- aggregation: 128-wide, one wave per node ----------------
// out[i] = f( dinv[i]^2*h[i] + sum_e norm[e]*h[src[e]] + bias )
// if hself != null: out[i] = (1-leader[i])*relu(agg+bias) + leader[i]*hself[i]
// else:             out[i] = relu(agg+bias)

__global__ __launch_bounds__(256) void agg128_kernel(const float* __restrict__ h,
                                                     const int* __restrict__ rstart, const int* __restrict__ cnt,
                                                     const int* __restrict__ csr_src, const float* __restrict__ csr_norm,
                                                     const float* __restrict__ dinv, const float* __restrict__ bias,
                                                     const float* __restrict__ hself, const float* __restrict__ leader,
                                                     float* __restrict__ out, int nnodes) {
  int wave = threadIdx.x >> 6;
  int lane = threadIdx.x & 63;
  int node = blockIdx.x * 4 + wave;
  if (node >= nnodes) return;
  int half = lane >> 5;   // which edge of the pair
  int q = lane & 31;      // column quad: cols 4q..4q+3
  const float* hq = h + 4 * q;

  float4 acc = make_float4(0.f, 0.f, 0.f, 0.f);
  float di = dinv[node];
  if (half == 0) {
    float s = di * di;
    float4 v = *(const float4*)(h + (size_t)node * 128 + 4 * q);
    acc.x = s * v.x; acc.y = s * v.y; acc.z = s * v.z; acc.w = s * v.w;
  }
  int rs = rstart[node];
  int n = cnt[node];
  for (int e = half; e < n; e += 2) {
    int s = csr_src[rs + e];
    float nrm = csr_norm[rs + e];
    float4 v = *(const float4*)(hq + (size_t)s * 128);
    acc.x += nrm * v.x; acc.y += nrm * v.y; acc.z += nrm * v.z; acc.w += nrm * v.w;
  }
  acc.x += __shfl_xor(acc.x, 32);
  acc.y += __shfl_xor(acc.y, 32);
  acc.z += __shfl_xor(acc.z, 32);
  acc.w += __shfl_xor(acc.w, 32);

  if (half == 0) {
    float4 b = *(const float4*)(bias + 4 * q);
    float4 r;
    r.x = fmaxf(acc.x + b.x, 0.f);
    r.y = fmaxf(acc.y + b.y, 0.f);
    r.z = fmaxf(acc.z + b.z, 0.f);
    r.w = fmaxf(acc.w + b.w, 0.f);
    if (hself) {
      float l = leader[node];
      float4 hs = *(const float4*)(hself + (size_t)node * 128 + 4 * q);
      r.x = (1.f - l) * r.x + l * hs.x;
      r.y = (1.f - l) * r.y + l * hs.y;
      r.z = (1.f - l) * r.z + l * hs.z;
      r.w = (1.f - l) * r.w + l * hs.w;
    }
    *(float4*)(out + (size_t)node * 128 + 4 * q) = r;
  }
}

// ---------------- aggregation: 64-wide leader conv + score head ----------------
// ls_h = relu(agg64 + bl); leader[i] = sigmoid(dot(ls_h, Wl2) + bl2)

__global__ __launch_bounds__(256) void agg64_leader_kernel(const float* __restrict__ h,
                                                           const int* __restrict__ rstart, const int* __restrict__ cnt,
                                                           const int* __restrict__ csr_src, const float* __restrict__ csr_norm,
                                                           const float* __restrict__ dinv, const float* __restrict__ bl,
                                                           const float* __restrict__ Wl2, const float* __restrict__ bl2,
                                                           float* __restrict__ leader_out, int nnodes) {
  int wave = threadIdx.x >> 6;
  int lane = threadIdx.x & 63;
  int node = blockIdx.x * 4 + wave;
  if (node >= nnodes) return;
  int g = lane >> 4;     // 4 edges in flight
  int q = lane & 15;     // cols 4q..4q+3
  const float* hq = h + 4 * q;

  float4 acc = make_float4(0.f, 0.f, 0.f, 0.f);
  float di = dinv[node];
  if (g == 0) {
    float s = di * di;
    float4 v = *(const float4*)(h + (size_t)node * 64 + 4 * q);
    acc.x = s * v.x; acc.y = s * v.y; acc.z = s * v.z; acc.w = s * v.w;
  }
  int rs = rstart[node];
  int n = cnt[node];
  for (int e = g; e < n; e += 4) {
    int s = csr_src[rs + e];
    float nrm = csr_norm[rs + e];
    float4 v = *(const float4*)(hq + (size_t)s * 64);
    acc.x += nrm * v.x; acc.y += nrm * v.y; acc.z += nrm * v.z; acc.w += nrm * v.w;
  }
#pragma unroll
  for (int m = 16; m <= 32; m <<= 1) {
    acc.x += __shfl_xor(acc.x, m);
    acc.y += __shfl_xor(acc.y, m);
    acc.z += __shfl_xor(acc.z, m);
    acc.w += __shfl_xor(acc.w, m);
  }
  float4 b = *(const float4*)(bl + 4 * q);
  float4 w2 = *(const float4*)(Wl2 + 4 * q);
  float part = fmaxf(acc.x + b.x, 0.f) * w2.x +
               fmaxf(acc.y + b.y, 0.f) * w2.y +
               fmaxf(acc.z + b.z, 0.f) * w2.z +
               fmaxf(acc.w + b.w, 0.f) * w2.w;
  part += __shfl_xor(part, 1);
  part += __shfl_xor(part, 2);
  part += __shfl_xor(part, 4);
  part += __shfl_xor(part, 8);
  if (lane == 0) {
    float z = part + bl2[0];
    leader_out[node] = 1.f / (1.f + expf(-z));
  }
}

// ---------------- host ----------------

extern "C" void kernel_launch(void* const* d_in, const int* in_sizes, int n_in,
                              void* d_out, int out_size, void* d_ws, size_t ws_size,
                              hipStream_t stream) {
  const float* x   = (const float*)d_in[0];
  const int*   ei  = (const int*)d_in[1];
  const float* ew  = (const float*)d_in[2];
  const float* W1  = (const float*)d_in[3];
  const float* b1  = (const float*)d_in[4];
  const float* W2  = (const float*)d_in[5];
  const float* b2  = (const float*)d_in[6];
  const float* Wsp = (const float*)d_in[7];
  const float* bs  = (const float*)d_in[8];
  const float* Wl  = (const float*)d_in[9];
  const float* bl  = (const float*)d_in[10];
  const float* Wl2 = (const float*)d_in[11];
  const float* bl2 = (const float*)d_in[12];

  const int N = in_sizes[0] / 128;   // 50000
  const int E = in_sizes[1] / 2;     // 800000

  char* ws = (char*)d_ws;
  size_t off = 0;
  auto alloc = [&](size_t bytes) -> void* {
    void* p = ws + off;
    off = (off + bytes + 255) & ~(size_t)255;
    return p;
  };
  float* deg      = (float*)alloc((size_t)N * 4);   // becomes dinv in place
  int*   cnt      = (int*)alloc((size_t)N * 4);
  int*   rstart   = (int*)alloc((size_t)N * 4);
  int*   cursor   = (int*)alloc((size_t)N * 4);
  int*   csr_src  = (int*)alloc((size_t)E * 4);
  float* csr_norm = (float*)alloc((size_t)E * 4);
  float* bufA     = (float*)alloc((size_t)N * 128 * 4);  // h1, then h2
  float* bufB     = (float*)alloc((size_t)N * 64 * 4);   // hl
  float* bufC     = (float*)alloc((size_t)N * 128 * 4);  // h_self_proj, then h_new

  float* h_final = (float*)d_out;
  float* leader  = (float*)d_out + (size_t)N * 128;

  int gN = (N + THREADS - 1) / THREADS;
  int gE = (E + THREADS - 1) / THREADS;

  // graph prep (shared by all three convs)
  init_kernel<<<gN, THREADS, 0, stream>>>(deg, cnt, cursor, N);
  edge_deg_kernel<<<gE, THREADS, 0, stream>>>(ei, ew, deg, cnt, E);
  dinv_kernel<<<gN, THREADS, 0, stream>>>(deg, N);
  scan_kernel<<<1, 1024, 0, stream>>>(cnt, rstart, N);
  csr_fill_kernel<<<gE, THREADS, 0, stream>>>(ei, ew, deg, rstart, cursor, csr_src, csr_norm, E);

  // GEMMs on x
  {
    dim3 g128((N + GBM - 1) / GBM, 128 / GBN);
    dim3 g64((N + GBM - 1) / GBM, 64 / GBN);
    gemm_k128<<<g128, 256, 0, stream>>>(x, W1, nullptr, bufA, N, 128);   // h1
    gemm_k128<<<g64, 256, 0, stream>>>(x, Wl, nullptr, bufB, N, 64);     // hl
    gemm_k128<<<g128, 256, 0, stream>>>(x, Wsp, bs, bufC, N, 128);       // h_self_proj
  }

  int gAgg = (N + 3) / 4;
  // leader score
  agg64_leader_kernel<<<gAgg, 256, 0, stream>>>(bufB, rstart, cnt, csr_src, csr_norm,
                                                deg, bl, Wl2, bl2, leader, N);
  // conv1 + relu + gated fusion -> h_new (overwrites bufC in place)
  agg128_kernel<<<gAgg, 256, 0, stream>>>(bufA, rstart, cnt, csr_src, csr_norm,
                                          deg, b1, bufC, leader, bufC, N);
  // h2 = h_new @ W2
  {
    dim3 g128((N + GBM - 1) / GBM, 128 / GBN);
    gemm_k128<<<g128, 256, 0, stream>>>(bufC, W2, nullptr, bufA, N, 128);
  }
  // conv2 + relu -> h_final
  agg128_kernel<<<gAgg, 256, 0, stream>>>(bufA, rstart, cnt, csr_src, csr_norm,
                                          deg, b2, nullptr, nullptr, h_final, N);
}

// Round 2
// 509.911 us; speedup vs baseline: 1.1231x; 1.1231x over previous
//
#include <hip/hip_runtime.h>
#include <math.h>

#define THREADS 256

// ---------------- setup kernels ----------------

__global__ __launch_bounds__(THREADS) void init_kernel(float* deg, int* cnt, int* cursor, int n) {
  int i = blockIdx.x * THREADS + threadIdx.x;
  if (i < n) { deg[i] = 1.0f; cnt[i] = 0; cursor[i] = 0; }
}

__global__ __launch_bounds__(THREADS) void edge_deg_kernel(const int* __restrict__ ei, const float* __restrict__ ew,
                                                           float* __restrict__ deg, int* __restrict__ cnt, int E) {
  int e = blockIdx.x * THREADS + threadIdx.x;
  if (e >= E) return;
  int d = ei[E + e];
  atomicAdd(deg + d, ew[e]);
  atomicAdd(cnt + d, 1);
}

__global__ __launch_bounds__(THREADS) void dinv_kernel(float* deg, int n) {
  int i = blockIdx.x * THREADS + threadIdx.x;
  if (i < n) deg[i] = rsqrtf(deg[i]);   // deg >= 1 always (self loop)
}

// ---------------- hierarchical exclusive scan of cnt -> rstart ----------------
// pass 1: each block scans 1024 elements (256 thr x 4), writes local-exclusive
//         prefixes + block total. pass 2: one wave scans the <=64 block totals.
// pass 3: add block prefix to every element.

__global__ __launch_bounds__(256) void scan1_kernel(const int* __restrict__ cnt, int* __restrict__ rstart,
                                                    int* __restrict__ bsum, int n) {
  int t = threadIdx.x;
  int lane = t & 63, wave = t >> 6;
  int base = blockIdx.x * 1024 + t * 4;
  int4 v = make_int4(0, 0, 0, 0);
  if (base + 3 < n) v = *(const int4*)(cnt + base);
  else if (base < n) {
    v.x = cnt[base];
    if (base + 1 < n) v.y = cnt[base + 1];
    if (base + 2 < n) v.z = cnt[base + 2];
  }
  int p1 = v.x, p2 = p1 + v.y, p3 = p2 + v.z, tsum = p3 + v.w;
  int incl = tsum;
#pragma unroll
  for (int off = 1; off < 64; off <<= 1) {
    int u = __shfl_up(incl, off);
    if (lane >= off) incl += u;
  }
  __shared__ int wt[4];
  if (lane == 63) wt[wave] = incl;
  __syncthreads();
  int wadd = 0;
#pragma unroll
  for (int w = 0; w < 4; w++) wadd += (w < wave) ? wt[w] : 0;
  int excl = wadd + incl - tsum;  // exclusive prefix of this thread's first elem
  if (base < n) {
    rstart[base] = excl;
    if (base + 1 < n) rstart[base + 1] = excl + p1;
    if (base + 2 < n) rstart[base + 2] = excl + p2;
    if (base + 3 < n) rstart[base + 3] = excl + p3;
  }
  if (t == 0) bsum[blockIdx.x] = 0;  // placeholder; real total below
  __syncthreads();
  if (t == 0) bsum[blockIdx.x] = wt[0] + wt[1] + wt[2] + wt[3];
}

__global__ __launch_bounds__(64) void scan2_kernel(const int* __restrict__ bsum, int* __restrict__ bpre, int nb) {
  int t = threadIdx.x;
  int v = (t < nb) ? bsum[t] : 0;
  int incl = v;
#pragma unroll
  for (int off = 1; off < 64; off <<= 1) {
    int u = __shfl_up(incl, off);
    if (t >= off) incl += u;
  }
  if (t < nb) bpre[t] = incl - v;  // exclusive
}

__global__ __launch_bounds__(256) void scan3_kernel(int* __restrict__ rstart, const int* __restrict__ bpre, int n) {
  int i = blockIdx.x * 256 + threadIdx.x;
  if (i < n) rstart[i] += bpre[i >> 10];
}

__global__ __launch_bounds__(THREADS) void csr_fill_kernel(const int* __restrict__ ei, const float* __restrict__ ew,
                                                           const float* __restrict__ dinv,
                                                           const int* __restrict__ rstart, int* __restrict__ cursor,
                                                           int* __restrict__ csr_src, float* __restrict__ csr_norm, int E) {
  int e = blockIdx.x * THREADS + threadIdx.x;
  if (e >= E) return;
  int s = ei[e];
  int d = ei[E + e];
  int pos = rstart[d] + atomicAdd(cursor + d, 1);
  csr_src[pos] = s;
  csr_norm[pos] = dinv[s] * ew[e] * dinv[d];
}

// ---------------- GEMM v2: C[M,N] = A[M,128] @ W[128,N] (+bias) ----------------
// 128xBN block, BK=32, 256 threads, 8x(4*CI) micro-tile. BN = 64*CI.

#define V2_BM 128
#define V2_BK 32

template <int CI>
__global__ __launch_bounds__(256) void gemm_v2(const float* __restrict__ A, const float* __restrict__ W,
                                               const float* __restrict__ bias, float* __restrict__ C,
                                               int M, int N) {
  constexpr int BN = 64 * CI;
  __shared__ float As[V2_BK][V2_BM];   // transposed: As[k][m]
  __shared__ float Ws[V2_BK][BN];      // Ws[k][n]
  int t = threadIdx.x;
  int bm = blockIdx.x * V2_BM;
  int bn = blockIdx.y * BN;
  int tx = t & 15, ty = t >> 4;

  float acc[2][4][CI][4] = {};

  for (int k0 = 0; k0 < 128; k0 += V2_BK) {
    if (k0) __syncthreads();
    {  // stage A tile (transpose): 128 rows x 32 k
      int m = t >> 1;
      int qb = (t & 1) * 4;
      const float* Ap = A + (size_t)(bm + m) * 128 + k0;
      bool ok = (bm + m) < M;
#pragma unroll
      for (int q = 0; q < 4; q++) {
        int qq = qb + q;
        float4 v = make_float4(0.f, 0.f, 0.f, 0.f);
        if (ok) v = *(const float4*)(Ap + 4 * qq);
        As[4 * qq + 0][m] = v.x;
        As[4 * qq + 1][m] = v.y;
        As[4 * qq + 2][m] = v.z;
        As[4 * qq + 3][m] = v.w;
      }
    }
    {  // stage W tile: 32 k-rows x BN cols
      int k = t >> 3;
      int qb = t & 7;
#pragma unroll
      for (int j = 0; j < BN / 32; j++) {
        int q = qb + 8 * j;
        float4 v = *(const float4*)(W + (size_t)(k0 + k) * N + bn + 4 * q);
        *(float4*)(&Ws[k][4 * q]) = v;
      }
    }
    __syncthreads();

#pragma unroll 8
    for (int k = 0; k < V2_BK; k++) {
      float a[2][4], b[CI][4];
      *(float4*)a[0] = *(const float4*)(&As[k][4 * ty]);
      *(float4*)a[1] = *(const float4*)(&As[k][64 + 4 * ty]);
#pragma unroll
      for (int ci = 0; ci < CI; ci++)
        *(float4*)b[ci] = *(const float4*)(&Ws[k][64 * ci + 4 * tx]);
#pragma unroll
      for (int ri = 0; ri < 2; ri++)
#pragma unroll
        for (int i = 0; i < 4; i++)
#pragma unroll
          for (int ci = 0; ci < CI; ci++)
#pragma unroll
            for (int j = 0; j < 4; j++)
              acc[ri][i][ci][j] += a[ri][i] * b[ci][j];
    }
  }

  float bv[CI][4];
#pragma unroll
  for (int ci = 0; ci < CI; ci++) {
    float4 z = make_float4(0.f, 0.f, 0.f, 0.f);
    if (bias) z = *(const float4*)(bias + bn + 64 * ci + 4 * tx);
    *(float4*)bv[ci] = z;
  }
#pragma unroll
  for (int ri = 0; ri < 2; ri++)
#pragma unroll
    for (int i = 0; i < 4; i++) {
      int row = bm + 64 * ri + 4 * ty + i;
      if (row < M) {
#pragma unroll
        for (int ci = 0; ci < CI; ci++) {
          float4 o;
          o.x = acc[ri][i][ci][0] + bv[ci][0];
          o.y = acc[ri][i][ci][1] + bv[ci][1];
          o.z = acc[ri][i][ci][2] + bv[ci][2];
          o.w = acc[ri][i][ci][3] + bv[ci][3];
          *(float4*)(C + (size_t)row * N + bn + 64 * ci + 4 * tx) = o;
        }
      }
    }
}

// ---------------- aggregation: 128-wide, one wave per node ----------------

__global__ __launch_bounds__(256) void agg128_kernel(const float* __restrict__ h,
                                                     const int* __restrict__ rstart, const int* __restrict__ cnt,
                                                     const int* __restrict__ csr_src, const float* __restrict__ csr_norm,
                                                     const float* __restrict__ dinv, const float* __restrict__ bias,
                                                     const float* __restrict__ hself, const float* __restrict__ leader,
                                                     float* __restrict__ out, int nnodes) {
  int wave = threadIdx.x >> 6;
  int lane = threadIdx.x & 63;
  int node = blockIdx.x * 4 + wave;
  if (node >= nnodes) return;
  int half = lane >> 5;
  int q = lane & 31;
  const float* hq = h + 4 * q;

  float4 acc = make_float4(0.f, 0.f, 0.f, 0.f);
  float di = dinv[node];
  if (half == 0) {
    float s = di * di;
    float4 v = *(const float4*)(h + (size_t)node * 128 + 4 * q);
    acc.x = s * v.x; acc.y = s * v.y; acc.z = s * v.z; acc.w = s * v.w;
  }
  int rs = rstart[node];
  int n = cnt[node];
  for (int e = half; e < n; e += 2) {
    int s = csr_src[rs + e];
    float nrm = csr_norm[rs + e];
    float4 v = *(const float4*)(hq + (size_t)s * 128);
    acc.x += nrm * v.x; acc.y += nrm * v.y; acc.z += nrm * v.z; acc.w += nrm * v.w;
  }
  acc.x += __shfl_xor(acc.x, 32);
  acc.y += __shfl_xor(acc.y, 32);
  acc.z += __shfl_xor(acc.z, 32);
  acc.w += __shfl_xor(acc.w, 32);

  if (half == 0) {
    float4 b = *(const float4*)(bias + 4 * q);
    float4 r;
    r.x = fmaxf(acc.x + b.x, 0.f);
    r.y = fmaxf(acc.y + b.y, 0.f);
    r.z = fmaxf(acc.z + b.z, 0.f);
    r.w = fmaxf(acc.w + b.w, 0.f);
    if (hself) {
      float l = leader[node];
      float4 hs = *(const float4*)(hself + (size_t)node * 128 + 4 * q);
      r.x = (1.f - l) * r.x + l * hs.x;
      r.y = (1.f - l) * r.y + l * hs.y;
      r.z = (1.f - l) * r.z + l * hs.z;
      r.w = (1.f - l) * r.w + l * hs.w;
    }
    *(float4*)(out + (size_t)node * 128 + 4 * q) = r;
  }
}

// ---------------- aggregation: 64-wide leader conv + score head ----------------

__global__ __launch_bounds__(256) void agg64_leader_kernel(const float* __restrict__ h,
                                                           const int* __restrict__ rstart, const int* __restrict__ cnt,
                                                           const int* __restrict__ csr_src, const float* __restrict__ csr_norm,
                                                           const float* __restrict__ dinv, const float* __restrict__ bl,
                                                           const float* __restrict__ Wl2, const float* __restrict__ bl2,
                                                           float* __restrict__ leader_out, int nnodes) {
  int wave = threadIdx.x >> 6;
  int lane = threadIdx.x & 63;
  int node = blockIdx.x * 4 + wave;
  if (node >= nnodes) return;
  int g = lane >> 4;
  int q = lane & 15;
  const float* hq = h + 4 * q;

  float4 acc = make_float4(0.f, 0.f, 0.f, 0.f);
  float di = dinv[node];
  if (g == 0) {
    float s = di * di;
    float4 v = *(const float4*)(h + (size_t)node * 64 + 4 * q);
    acc.x = s * v.x; acc.y = s * v.y; acc.z = s * v.z; acc.w = s * v.w;
  }
  int rs = rstart[node];
  int n = cnt[node];
  for (int e = g; e < n; e += 4) {
    int s = csr_src[rs + e];
    float nrm = csr_norm[rs + e];
    float4 v = *(const float4*)(hq + (size_t)s * 64);
    acc.x += nrm * v.x; acc.y += nrm * v.y; acc.z += nrm * v.z; acc.w += nrm * v.w;
  }
#pragma unroll
  for (int m = 16; m <= 32; m <<= 1) {
    acc.x += __shfl_xor(acc.x, m);
    acc.y += __shfl_xor(acc.y, m);
    acc.z += __shfl_xor(acc.z, m);
    acc.w += __shfl_xor(acc.w, m);
  }
  float4 b = *(const float4*)(bl + 4 * q);
  float4 w2 = *(const float4*)(Wl2 + 4 * q);
  float part = fmaxf(acc.x + b.x, 0.f) * w2.x +
               fmaxf(acc.y + b.y, 0.f) * w2.y +
               fmaxf(acc.z + b.z, 0.f) * w2.z +
               fmaxf(acc.w + b.w, 0.f) * w2.w;
  part += __shfl_xor(part, 1);
  part += __shfl_xor(part, 2);
  part += __shfl_xor(part, 4);
  part += __shfl_xor(part, 8);
  if (lane == 0) {
    float z = part + bl2[0];
    leader_out[node] = 1.f / (1.f + expf(-z));
  }
}

// ---------------- host ----------------

extern "C" void kernel_launch(void* const* d_in, const int* in_sizes, int n_in,
                              void* d_out, int out_size, void* d_ws, size_t ws_size,
                              hipStream_t stream) {
  const float* x   = (const float*)d_in[0];
  const int*   ei  = (const int*)d_in[1];
  const float* ew  = (const float*)d_in[2];
  const float* W1  = (const float*)d_in[3];
  const float* b1  = (const float*)d_in[4];
  const float* W2  = (const float*)d_in[5];
  const float* b2  = (const float*)d_in[6];
  const float* Wsp = (const float*)d_in[7];
  const float* bs  = (const float*)d_in[8];
  const float* Wl  = (const float*)d_in[9];
  const float* bl  = (const float*)d_in[10];
  const float* Wl2 = (const float*)d_in[11];
  const float* bl2 = (const float*)d_in[12];

  const int N = in_sizes[0] / 128;   // 50000
  const int E = in_sizes[1] / 2;     // 800000

  char* ws = (char*)d_ws;
  size_t off = 0;
  auto alloc = [&](size_t bytes) -> void* {
    void* p = ws + off;
    off = (off + bytes + 255) & ~(size_t)255;
    return p;
  };
  float* deg      = (float*)alloc((size_t)N * 4);   // becomes dinv in place
  int*   cnt      = (int*)alloc((size_t)N * 4);
  int*   rstart   = (int*)alloc((size_t)N * 4);
  int*   cursor   = (int*)alloc((size_t)N * 4);
  int*   csr_src  = (int*)alloc((size_t)E * 4);
  float* csr_norm = (float*)alloc((size_t)E * 4);
  float* bufA     = (float*)alloc((size_t)N * 128 * 4);  // h1, then h2
  float* bufB     = (float*)alloc((size_t)N * 64 * 4);   // hl
  float* bufC     = (float*)alloc((size_t)N * 128 * 4);  // h_self_proj, then h_new
  int*   bsum     = (int*)alloc(256 * 4);
  int*   bpre     = (int*)alloc(256 * 4);

  float* h_final = (float*)d_out;
  float* leader  = (float*)d_out + (size_t)N * 128;

  int gN = (N + THREADS - 1) / THREADS;
  int gE = (E + THREADS - 1) / THREADS;
  int nScanBlocks = (N + 1023) / 1024;   // 49 <= 64

  // graph prep (shared by all three convs)
  init_kernel<<<gN, THREADS, 0, stream>>>(deg, cnt, cursor, N);
  edge_deg_kernel<<<gE, THREADS, 0, stream>>>(ei, ew, deg, cnt, E);
  dinv_kernel<<<gN, THREADS, 0, stream>>>(deg, N);
  scan1_kernel<<<nScanBlocks, 256, 0, stream>>>(cnt, rstart, bsum, N);
  scan2_kernel<<<1, 64, 0, stream>>>(bsum, bpre, nScanBlocks);
  scan3_kernel<<<gN, 256, 0, stream>>>(rstart, bpre, N);
  csr_fill_kernel<<<gE, THREADS, 0, stream>>>(ei, ew, deg, rstart, cursor, csr_src, csr_norm, E);

  // GEMMs on x
  int gm = (N + V2_BM - 1) / V2_BM;
  gemm_v2<2><<<dim3(gm, 1), 256, 0, stream>>>(x, W1, nullptr, bufA, N, 128);   // h1
  gemm_v2<1><<<dim3(gm, 1), 256, 0, stream>>>(x, Wl, nullptr, bufB, N, 64);    // hl
  gemm_v2<2><<<dim3(gm, 1), 256, 0, stream>>>(x, Wsp, bs, bufC, N, 128);       // h_self_proj

  int gAgg = (N + 3) / 4;
  // leader score
  agg64_leader_kernel<<<gAgg, 256, 0, stream>>>(bufB, rstart, cnt, csr_src, csr_norm,
                                                deg, bl, Wl2, bl2, leader, N);
  // conv1 + relu + gated fusion -> h_new (overwrites bufC in place)
  agg128_kernel<<<gAgg, 256, 0, stream>>>(bufA, rstart, cnt, csr_src, csr_norm,
                                          deg, b1, bufC, leader, bufC, N);
  // h2 = h_new @ W2
  gemm_v2<2><<<dim3(gm, 1), 256, 0, stream>>>(bufC, W2, nullptr, bufA, N, 128);
  // conv2 + relu -> h_final
  agg128_kernel<<<gAgg, 256, 0, stream>>>(bufA, rstart, cnt, csr_src, csr_norm,
                                          deg, b2, nullptr, nullptr, h_final, N);
}

// Round 3
// 454.334 us; speedup vs baseline: 1.2605x; 1.1223x over previous
//
#include <hip/hip_runtime.h>
#include <math.h>

#define THREADS 256

// ---------------- setup kernels ----------------

__global__ __launch_bounds__(THREADS) void init_kernel(int* cnt, int n) {
  int i = blockIdx.x * THREADS + threadIdx.x;
  if (i < n) cnt[i] = 0;
}

// one atomic per edge: returned old count = slot within dst bucket
__global__ __launch_bounds__(THREADS) void edge_off_kernel(const int* __restrict__ ei,
                                                           int* __restrict__ cnt,
                                                           int* __restrict__ local_off, int E) {
  int e = blockIdx.x * THREADS + threadIdx.x;
  if (e >= E) return;
  int d = ei[E + e];
  local_off[e] = atomicAdd(cnt + d, 1);
}

// ---------------- hierarchical exclusive scan of cnt -> rstart ----------------

__global__ __launch_bounds__(256) void scan1_kernel(const int* __restrict__ cnt, int* __restrict__ rstart,
                                                    int* __restrict__ bsum, int n) {
  int t = threadIdx.x;
  int lane = t & 63, wave = t >> 6;
  int base = blockIdx.x * 1024 + t * 4;
  int4 v = make_int4(0, 0, 0, 0);
  if (base + 3 < n) v = *(const int4*)(cnt + base);
  else if (base < n) {
    v.x = cnt[base];
    if (base + 1 < n) v.y = cnt[base + 1];
    if (base + 2 < n) v.z = cnt[base + 2];
  }
  int p1 = v.x, p2 = p1 + v.y, p3 = p2 + v.z, tsum = p3 + v.w;
  int incl = tsum;
#pragma unroll
  for (int off = 1; off < 64; off <<= 1) {
    int u = __shfl_up(incl, off);
    if (lane >= off) incl += u;
  }
  __shared__ int wt[4];
  if (lane == 63) wt[wave] = incl;
  __syncthreads();
  int wadd = 0;
#pragma unroll
  for (int w = 0; w < 4; w++) wadd += (w < wave) ? wt[w] : 0;
  int excl = wadd + incl - tsum;
  if (base < n) {
    rstart[base] = excl;
    if (base + 1 < n) rstart[base + 1] = excl + p1;
    if (base + 2 < n) rstart[base + 2] = excl + p2;
    if (base + 3 < n) rstart[base + 3] = excl + p3;
  }
  if (t == 0) bsum[blockIdx.x] = wt[0] + wt[1] + wt[2] + wt[3];
}

__global__ __launch_bounds__(64) void scan2_kernel(const int* __restrict__ bsum, int* __restrict__ bpre, int nb) {
  int t = threadIdx.x;
  int v = (t < nb) ? bsum[t] : 0;
  int incl = v;
#pragma unroll
  for (int off = 1; off < 64; off <<= 1) {
    int u = __shfl_up(incl, off);
    if (t >= off) incl += u;
  }
  if (t < nb) bpre[t] = incl - v;
}

__global__ __launch_bounds__(256) void scan3_kernel(int* __restrict__ rstart, const int* __restrict__ bpre, int n) {
  int i = blockIdx.x * 256 + threadIdx.x;
  if (i < n) rstart[i] += bpre[i >> 10];
}

// ---------------- CSR build: no atomics, packed {src, w} ----------------

__global__ __launch_bounds__(THREADS) void csr_build_kernel(const int* __restrict__ ei, const float* __restrict__ ew,
                                                            const int* __restrict__ rstart, const int* __restrict__ local_off,
                                                            int2* __restrict__ csr, int E) {
  int e = blockIdx.x * THREADS + threadIdx.x;
  if (e >= E) return;
  int s = ei[e];
  int d = ei[E + e];
  int pos = rstart[d] + local_off[e];
  csr[pos] = make_int2(s, __float_as_int(ew[e]));
}

// weighted degree from CSR rows (coalesced) -> dinv, wave per node
__global__ __launch_bounds__(256) void deg_wave_kernel(const int2* __restrict__ csr,
                                                       const int* __restrict__ rstart, const int* __restrict__ cnt,
                                                       float* __restrict__ dinv, int nnodes) {
  int wave = threadIdx.x >> 6, lane = threadIdx.x & 63;
  int node = blockIdx.x * 4 + wave;
  if (node >= nnodes) return;
  int rs = rstart[node], c = cnt[node];
  float s = 0.f;
  for (int i = lane; i < c; i += 64) s += __int_as_float(csr[rs + i].y);
#pragma unroll
  for (int m = 32; m; m >>= 1) s += __shfl_xor(s, m);
  if (lane == 0) dinv[node] = rsqrtf(1.0f + s);   // +1 = self loop weight
}

// rewrite w -> dinv[src]*w*dinv[dst] in place, wave per node
__global__ __launch_bounds__(256) void norm_wave_kernel(int2* __restrict__ csr,
                                                        const int* __restrict__ rstart, const int* __restrict__ cnt,
                                                        const float* __restrict__ dinv, int nnodes) {
  int wave = threadIdx.x >> 6, lane = threadIdx.x & 63;
  int node = blockIdx.x * 4 + wave;
  if (node >= nnodes) return;
  int rs = rstart[node], c = cnt[node];
  float dd = dinv[node];
  for (int i = lane; i < c; i += 64) {
    int2 en = csr[rs + i];
    float w = __int_as_float(en.y);
    csr[rs + i].y = __float_as_int(dinv[en.x] * w * dd);
  }
}

// ---------------- GEMM v2: C[M,N] = A[M,128] @ W[128,N] (+bias) ----------------

#define V2_BM 128
#define V2_BK 32

template <int CI>
__global__ __launch_bounds__(256) void gemm_v2(const float* __restrict__ A, const float* __restrict__ W,
                                               const float* __restrict__ bias, float* __restrict__ C,
                                               int M, int N) {
  constexpr int BN = 64 * CI;
  __shared__ float As[V2_BK][V2_BM];
  __shared__ float Ws[V2_BK][BN];
  int t = threadIdx.x;
  int bm = blockIdx.x * V2_BM;
  int bn = blockIdx.y * BN;
  int tx = t & 15, ty = t >> 4;

  float acc[2][4][CI][4] = {};

  for (int k0 = 0; k0 < 128; k0 += V2_BK) {
    if (k0) __syncthreads();
    {
      int m = t >> 1;
      int qb = (t & 1) * 4;
      const float* Ap = A + (size_t)(bm + m) * 128 + k0;
      bool ok = (bm + m) < M;
#pragma unroll
      for (int q = 0; q < 4; q++) {
        int qq = qb + q;
        float4 v = make_float4(0.f, 0.f, 0.f, 0.f);
        if (ok) v = *(const float4*)(Ap + 4 * qq);
        As[4 * qq + 0][m] = v.x;
        As[4 * qq + 1][m] = v.y;
        As[4 * qq + 2][m] = v.z;
        As[4 * qq + 3][m] = v.w;
      }
    }
    {
      int k = t >> 3;
      int qb = t & 7;
#pragma unroll
      for (int j = 0; j < BN / 32; j++) {
        int q = qb + 8 * j;
        float4 v = *(const float4*)(W + (size_t)(k0 + k) * N + bn + 4 * q);
        *(float4*)(&Ws[k][4 * q]) = v;
      }
    }
    __syncthreads();

#pragma unroll 8
    for (int k = 0; k < V2_BK; k++) {
      float a[2][4], b[CI][4];
      *(float4*)a[0] = *(const float4*)(&As[k][4 * ty]);
      *(float4*)a[1] = *(const float4*)(&As[k][64 + 4 * ty]);
#pragma unroll
      for (int ci = 0; ci < CI; ci++)
        *(float4*)b[ci] = *(const float4*)(&Ws[k][64 * ci + 4 * tx]);
#pragma unroll
      for (int ri = 0; ri < 2; ri++)
#pragma unroll
        for (int i = 0; i < 4; i++)
#pragma unroll
          for (int ci = 0; ci < CI; ci++)
#pragma unroll
            for (int j = 0; j < 4; j++)
              acc[ri][i][ci][j] += a[ri][i] * b[ci][j];
    }
  }

  float bv[CI][4];
#pragma unroll
  for (int ci = 0; ci < CI; ci++) {
    float4 z = make_float4(0.f, 0.f, 0.f, 0.f);
    if (bias) z = *(const float4*)(bias + bn + 64 * ci + 4 * tx);
    *(float4*)bv[ci] = z;
  }
#pragma unroll
  for (int ri = 0; ri < 2; ri++)
#pragma unroll
    for (int i = 0; i < 4; i++) {
      int row = bm + 64 * ri + 4 * ty + i;
      if (row < M) {
#pragma unroll
        for (int ci = 0; ci < CI; ci++) {
          float4 o;
          o.x = acc[ri][i][ci][0] + bv[ci][0];
          o.y = acc[ri][i][ci][1] + bv[ci][1];
          o.z = acc[ri][i][ci][2] + bv[ci][2];
          o.w = acc[ri][i][ci][3] + bv[ci][3];
          *(float4*)(C + (size_t)row * N + bn + 64 * ci + 4 * tx) = o;
        }
      }
    }
}

// ---------------- aggregation: 128-wide, one wave per node ----------------

__global__ __launch_bounds__(256) void agg128_kernel(const float* __restrict__ h,
                                                     const int* __restrict__ rstart, const int* __restrict__ cnt,
                                                     const int2* __restrict__ csr,
                                                     const float* __restrict__ dinv, const float* __restrict__ bias,
                                                     const float* __restrict__ hself, const float* __restrict__ leader,
                                                     float* __restrict__ out, int nnodes) {
  int wave = threadIdx.x >> 6;
  int lane = threadIdx.x & 63;
  int node = blockIdx.x * 4 + wave;
  if (node >= nnodes) return;
  int half = lane >> 5;
  int q = lane & 31;
  const float* hq = h + 4 * q;

  float4 acc = make_float4(0.f, 0.f, 0.f, 0.f);
  float di = dinv[node];
  if (half == 0) {
    float s = di * di;
    float4 v = *(const float4*)(h + (size_t)node * 128 + 4 * q);
    acc.x = s * v.x; acc.y = s * v.y; acc.z = s * v.z; acc.w = s * v.w;
  }
  int rs = rstart[node];
  int n = cnt[node];
  for (int e = half; e < n; e += 2) {
    int2 en = csr[rs + e];
    float nrm = __int_as_float(en.y);
    float4 v = *(const float4*)(hq + (size_t)en.x * 128);
    acc.x += nrm * v.x; acc.y += nrm * v.y; acc.z += nrm * v.z; acc.w += nrm * v.w;
  }
  acc.x += __shfl_xor(acc.x, 32);
  acc.y += __shfl_xor(acc.y, 32);
  acc.z += __shfl_xor(acc.z, 32);
  acc.w += __shfl_xor(acc.w, 32);

  if (half == 0) {
    float4 b = *(const float4*)(bias + 4 * q);
    float4 r;
    r.x = fmaxf(acc.x + b.x, 0.f);
    r.y = fmaxf(acc.y + b.y, 0.f);
    r.z = fmaxf(acc.z + b.z, 0.f);
    r.w = fmaxf(acc.w + b.w, 0.f);
    if (hself) {
      float l = leader[node];
      float4 hs = *(const float4*)(hself + (size_t)node * 128 + 4 * q);
      r.x = (1.f - l) * r.x + l * hs.x;
      r.y = (1.f - l) * r.y + l * hs.y;
      r.z = (1.f - l) * r.z + l * hs.z;
      r.w = (1.f - l) * r.w + l * hs.w;
    }
    *(float4*)(out + (size_t)node * 128 + 4 * q) = r;
  }
}

// ---------------- aggregation: 64-wide leader conv + score head ----------------

__global__ __launch_bounds__(256) void agg64_leader_kernel(const float* __restrict__ h,
                                                           const int* __restrict__ rstart, const int* __restrict__ cnt,
                                                           const int2* __restrict__ csr,
                                                           const float* __restrict__ dinv, const float* __restrict__ bl,
                                                           const float* __restrict__ Wl2, const float* __restrict__ bl2,
                                                           float* __restrict__ leader_out, int nnodes) {
  int wave = threadIdx.x >> 6;
  int lane = threadIdx.x & 63;
  int node = blockIdx.x * 4 + wave;
  if (node >= nnodes) return;
  int g = lane >> 4;
  int q = lane & 15;
  const float* hq = h + 4 * q;

  float4 acc = make_float4(0.f, 0.f, 0.f, 0.f);
  float di = dinv[node];
  if (g == 0) {
    float s = di * di;
    float4 v = *(const float4*)(h + (size_t)node * 64 + 4 * q);
    acc.x = s * v.x; acc.y = s * v.y; acc.z = s * v.z; acc.w = s * v.w;
  }
  int rs = rstart[node];
  int n = cnt[node];
  for (int e = g; e < n; e += 4) {
    int2 en = csr[rs + e];
    float nrm = __int_as_float(en.y);
    float4 v = *(const float4*)(hq + (size_t)en.x * 64);
    acc.x += nrm * v.x; acc.y += nrm * v.y; acc.z += nrm * v.z; acc.w += nrm * v.w;
  }
#pragma unroll
  for (int m = 16; m <= 32; m <<= 1) {
    acc.x += __shfl_xor(acc.x, m);
    acc.y += __shfl_xor(acc.y, m);
    acc.z += __shfl_xor(acc.z, m);
    acc.w += __shfl_xor(acc.w, m);
  }
  float4 b = *(const float4*)(bl + 4 * q);
  float4 w2 = *(const float4*)(Wl2 + 4 * q);
  float part = fmaxf(acc.x + b.x, 0.f) * w2.x +
               fmaxf(acc.y + b.y, 0.f) * w2.y +
               fmaxf(acc.z + b.z, 0.f) * w2.z +
               fmaxf(acc.w + b.w, 0.f) * w2.w;
  part += __shfl_xor(part, 1);
  part += __shfl_xor(part, 2);
  part += __shfl_xor(part, 4);
  part += __shfl_xor(part, 8);
  if (lane == 0) {
    float z = part + bl2[0];
    leader_out[node] = 1.f / (1.f + expf(-z));
  }
}

// ---------------- host ----------------

extern "C" void kernel_launch(void* const* d_in, const int* in_sizes, int n_in,
                              void* d_out, int out_size, void* d_ws, size_t ws_size,
                              hipStream_t stream) {
  const float* x   = (const float*)d_in[0];
  const int*   ei  = (const int*)d_in[1];
  const float* ew  = (const float*)d_in[2];
  const float* W1  = (const float*)d_in[3];
  const float* b1  = (const float*)d_in[4];
  const float* W2  = (const float*)d_in[5];
  const float* b2  = (const float*)d_in[6];
  const float* Wsp = (const float*)d_in[7];
  const float* bs  = (const float*)d_in[8];
  const float* Wl  = (const float*)d_in[9];
  const float* bl  = (const float*)d_in[10];
  const float* Wl2 = (const float*)d_in[11];
  const float* bl2 = (const float*)d_in[12];

  const int N = in_sizes[0] / 128;   // 50000
  const int E = in_sizes[1] / 2;     // 800000

  char* ws = (char*)d_ws;
  size_t off = 0;
  auto alloc = [&](size_t bytes) -> void* {
    void* p = ws + off;
    off = (off + bytes + 255) & ~(size_t)255;
    return p;
  };
  float* dinv      = (float*)alloc((size_t)N * 4);
  int*   cnt       = (int*)alloc((size_t)N * 4);
  int*   rstart    = (int*)alloc((size_t)N * 4);
  int*   local_off = (int*)alloc((size_t)E * 4);
  int2*  csr       = (int2*)alloc((size_t)E * 8);
  float* bufA      = (float*)alloc((size_t)N * 128 * 4);  // h1, then h2
  float* bufB      = (float*)alloc((size_t)N * 64 * 4);   // hl
  float* bufC      = (float*)alloc((size_t)N * 128 * 4);  // h_self_proj, then h_new
  int*   bsum      = (int*)alloc(256 * 4);
  int*   bpre      = (int*)alloc(256 * 4);

  float* h_final = (float*)d_out;
  float* leader  = (float*)d_out + (size_t)N * 128;

  int gN = (N + THREADS - 1) / THREADS;
  int gE = (E + THREADS - 1) / THREADS;
  int nScanBlocks = (N + 1023) / 1024;   // 49 <= 64
  int gWave = (N + 3) / 4;

  // graph prep (shared by all three convs) — exactly one atomic per edge
  init_kernel<<<gN, THREADS, 0, stream>>>(cnt, N);
  edge_off_kernel<<<gE, THREADS, 0, stream>>>(ei, cnt, local_off, E);
  scan1_kernel<<<nScanBlocks, 256, 0, stream>>>(cnt, rstart, bsum, N);
  scan2_kernel<<<1, 64, 0, stream>>>(bsum, bpre, nScanBlocks);
  scan3_kernel<<<gN, 256, 0, stream>>>(rstart, bpre, N);
  csr_build_kernel<<<gE, THREADS, 0, stream>>>(ei, ew, rstart, local_off, csr, E);
  deg_wave_kernel<<<gWave, 256, 0, stream>>>(csr, rstart, cnt, dinv, N);
  norm_wave_kernel<<<gWave, 256, 0, stream>>>(csr, rstart, cnt, dinv, N);

  // GEMMs on x
  int gm = (N + V2_BM - 1) / V2_BM;
  gemm_v2<2><<<dim3(gm, 1), 256, 0, stream>>>(x, W1, nullptr, bufA, N, 128);   // h1
  gemm_v2<1><<<dim3(gm, 1), 256, 0, stream>>>(x, Wl, nullptr, bufB, N, 64);    // hl
  gemm_v2<2><<<dim3(gm, 1), 256, 0, stream>>>(x, Wsp, bs, bufC, N, 128);       // h_self_proj

  // leader score
  agg64_leader_kernel<<<gWave, 256, 0, stream>>>(bufB, rstart, cnt, csr,
                                                 dinv, bl, Wl2, bl2, leader, N);
  // conv1 + relu + gated fusion -> h_new (overwrites bufC in place)
  agg128_kernel<<<gWave, 256, 0, stream>>>(bufA, rstart, cnt, csr,
                                           dinv, b1, bufC, leader, bufC, N);
  // h2 = h_new @ W2
  gemm_v2<2><<<dim3(gm, 1), 256, 0, stream>>>(bufC, W2, nullptr, bufA, N, 128);
  // conv2 + relu -> h_final
  agg128_kernel<<<gWave, 256, 0, stream>>>(bufA, rstart, cnt, csr,
                                           dinv, b2, nullptr, nullptr, h_final, N);
}

// Round 4
// 398.438 us; speedup vs baseline: 1.4373x; 1.1403x over previous
//
#include <hip/hip_runtime.h>
#include <math.h>

#define THREADS 256

typedef unsigned int uint32;
typedef unsigned short ushort16;

__device__ __forceinline__ unsigned short f2bf_rne(float x) {
  uint32 u = __float_as_uint(x);
  u += 0x7fffu + ((u >> 16) & 1u);
  return (unsigned short)(u >> 16);
}

__device__ __forceinline__ void unpack8(uint4 v, float* f) {
  f[0] = __uint_as_float(v.x << 16);
  f[1] = __uint_as_float(v.x & 0xffff0000u);
  f[2] = __uint_as_float(v.y << 16);
  f[3] = __uint_as_float(v.y & 0xffff0000u);
  f[4] = __uint_as_float(v.z << 16);
  f[5] = __uint_as_float(v.z & 0xffff0000u);
  f[6] = __uint_as_float(v.w << 16);
  f[7] = __uint_as_float(v.w & 0xffff0000u);
}

// ---------------- setup kernels ----------------

__global__ __launch_bounds__(THREADS) void init_kernel(int* cnt, int n) {
  int i = blockIdx.x * THREADS + threadIdx.x;
  if (i < n) cnt[i] = 0;
}

__global__ __launch_bounds__(THREADS) void edge_off_kernel(const int* __restrict__ ei,
                                                           int* __restrict__ cnt,
                                                           int* __restrict__ local_off, int E) {
  int e = blockIdx.x * THREADS + threadIdx.x;
  if (e >= E) return;
  int d = ei[E + e];
  local_off[e] = atomicAdd(cnt + d, 1);
}

// ---------------- hierarchical exclusive scan of cnt -> rstart ----------------

__global__ __launch_bounds__(256) void scan1_kernel(const int* __restrict__ cnt, int* __restrict__ rstart,
                                                    int* __restrict__ bsum, int n) {
  int t = threadIdx.x;
  int lane = t & 63, wave = t >> 6;
  int base = blockIdx.x * 1024 + t * 4;
  int4 v = make_int4(0, 0, 0, 0);
  if (base + 3 < n) v = *(const int4*)(cnt + base);
  else if (base < n) {
    v.x = cnt[base];
    if (base + 1 < n) v.y = cnt[base + 1];
    if (base + 2 < n) v.z = cnt[base + 2];
  }
  int p1 = v.x, p2 = p1 + v.y, p3 = p2 + v.z, tsum = p3 + v.w;
  int incl = tsum;
#pragma unroll
  for (int off = 1; off < 64; off <<= 1) {
    int u = __shfl_up(incl, off);
    if (lane >= off) incl += u;
  }
  __shared__ int wt[4];
  if (lane == 63) wt[wave] = incl;
  __syncthreads();
  int wadd = 0;
#pragma unroll
  for (int w = 0; w < 4; w++) wadd += (w < wave) ? wt[w] : 0;
  int excl = wadd + incl - tsum;
  if (base < n) {
    rstart[base] = excl;
    if (base + 1 < n) rstart[base + 1] = excl + p1;
    if (base + 2 < n) rstart[base + 2] = excl + p2;
    if (base + 3 < n) rstart[base + 3] = excl + p3;
  }
  if (t == 0) bsum[blockIdx.x] = wt[0] + wt[1] + wt[2] + wt[3];
}

__global__ __launch_bounds__(64) void scan2_kernel(const int* __restrict__ bsum, int* __restrict__ bpre, int nb) {
  int t = threadIdx.x;
  int v = (t < nb) ? bsum[t] : 0;
  int incl = v;
#pragma unroll
  for (int off = 1; off < 64; off <<= 1) {
    int u = __shfl_up(incl, off);
    if (t >= off) incl += u;
  }
  if (t < nb) bpre[t] = incl - v;
}

__global__ __launch_bounds__(256) void scan3_kernel(int* __restrict__ rstart, const int* __restrict__ bpre, int n) {
  int i = blockIdx.x * 256 + threadIdx.x;
  if (i < n) rstart[i] += bpre[i >> 10];
}

// ---------------- CSR build: no atomics, packed {src, w} ----------------

__global__ __launch_bounds__(THREADS) void csr_build_kernel(const int* __restrict__ ei, const float* __restrict__ ew,
                                                            const int* __restrict__ rstart, const int* __restrict__ local_off,
                                                            int2* __restrict__ csr, int E) {
  int e = blockIdx.x * THREADS + threadIdx.x;
  if (e >= E) return;
  int s = ei[e];
  int d = ei[E + e];
  int pos = rstart[d] + local_off[e];
  csr[pos] = make_int2(s, __float_as_int(ew[e]));
}

__global__ __launch_bounds__(256) void deg_wave_kernel(const int2* __restrict__ csr,
                                                       const int* __restrict__ rstart, const int* __restrict__ cnt,
                                                       float* __restrict__ dinv, int nnodes) {
  int wave = threadIdx.x >> 6, lane = threadIdx.x & 63;
  int node = blockIdx.x * 4 + wave;
  if (node >= nnodes) return;
  int rs = rstart[node], c = cnt[node];
  float s = 0.f;
  for (int i = lane; i < c; i += 64) s += __int_as_float(csr[rs + i].y);
#pragma unroll
  for (int m = 32; m; m >>= 1) s += __shfl_xor(s, m);
  if (lane == 0) dinv[node] = rsqrtf(1.0f + s);
}

__global__ __launch_bounds__(256) void norm_wave_kernel(int2* __restrict__ csr,
                                                        const int* __restrict__ rstart, const int* __restrict__ cnt,
                                                        const float* __restrict__ dinv, int nnodes) {
  int wave = threadIdx.x >> 6, lane = threadIdx.x & 63;
  int node = blockIdx.x * 4 + wave;
  if (node >= nnodes) return;
  int rs = rstart[node], c = cnt[node];
  float dd = dinv[node];
  for (int i = lane; i < c; i += 64) {
    int2 en = csr[rs + i];
    float w = __int_as_float(en.y);
    csr[rs + i].y = __float_as_int(dinv[en.x] * w * dd);
  }
}

// ---------------- GEMM v2: C[M,N] = A[M,128] @ W[128,N] (+bias) ----------------
// BF16OUT: write bf16 (for gather consumers); else fp32.

#define V2_BM 128
#define V2_BK 32

template <int CI, bool BF16OUT>
__global__ __launch_bounds__(256) void gemm_v2(const float* __restrict__ A, const float* __restrict__ W,
                                               const float* __restrict__ bias, void* __restrict__ Cv,
                                               int M, int N) {
  constexpr int BN = 64 * CI;
  __shared__ float As[V2_BK][V2_BM];
  __shared__ float Ws[V2_BK][BN];
  int t = threadIdx.x;
  int bm = blockIdx.x * V2_BM;
  int bn = blockIdx.y * BN;
  int tx = t & 15, ty = t >> 4;

  float acc[2][4][CI][4] = {};

  for (int k0 = 0; k0 < 128; k0 += V2_BK) {
    if (k0) __syncthreads();
    {
      int m = t >> 1;
      int qb = (t & 1) * 4;
      const float* Ap = A + (size_t)(bm + m) * 128 + k0;
      bool ok = (bm + m) < M;
#pragma unroll
      for (int q = 0; q < 4; q++) {
        int qq = qb + q;
        float4 v = make_float4(0.f, 0.f, 0.f, 0.f);
        if (ok) v = *(const float4*)(Ap + 4 * qq);
        As[4 * qq + 0][m] = v.x;
        As[4 * qq + 1][m] = v.y;
        As[4 * qq + 2][m] = v.z;
        As[4 * qq + 3][m] = v.w;
      }
    }
    {
      int k = t >> 3;
      int qb = t & 7;
#pragma unroll
      for (int j = 0; j < BN / 32; j++) {
        int q = qb + 8 * j;
        float4 v = *(const float4*)(W + (size_t)(k0 + k) * N + bn + 4 * q);
        *(float4*)(&Ws[k][4 * q]) = v;
      }
    }
    __syncthreads();

#pragma unroll 8
    for (int k = 0; k < V2_BK; k++) {
      float a[2][4], b[CI][4];
      *(float4*)a[0] = *(const float4*)(&As[k][4 * ty]);
      *(float4*)a[1] = *(const float4*)(&As[k][64 + 4 * ty]);
#pragma unroll
      for (int ci = 0; ci < CI; ci++)
        *(float4*)b[ci] = *(const float4*)(&Ws[k][64 * ci + 4 * tx]);
#pragma unroll
      for (int ri = 0; ri < 2; ri++)
#pragma unroll
        for (int i = 0; i < 4; i++)
#pragma unroll
          for (int ci = 0; ci < CI; ci++)
#pragma unroll
            for (int j = 0; j < 4; j++)
              acc[ri][i][ci][j] += a[ri][i] * b[ci][j];
    }
  }

  float bv[CI][4];
#pragma unroll
  for (int ci = 0; ci < CI; ci++) {
    float4 z = make_float4(0.f, 0.f, 0.f, 0.f);
    if (bias) z = *(const float4*)(bias + bn + 64 * ci + 4 * tx);
    *(float4*)bv[ci] = z;
  }
#pragma unroll
  for (int ri = 0; ri < 2; ri++)
#pragma unroll
    for (int i = 0; i < 4; i++) {
      int row = bm + 64 * ri + 4 * ty + i;
      if (row < M) {
#pragma unroll
        for (int ci = 0; ci < CI; ci++) {
          float o[4];
#pragma unroll
          for (int j = 0; j < 4; j++) o[j] = acc[ri][i][ci][j] + bv[ci][j];
          if (BF16OUT) {
            unsigned short* C = (unsigned short*)Cv;
            ushort4 p;
            p.x = f2bf_rne(o[0]); p.y = f2bf_rne(o[1]);
            p.z = f2bf_rne(o[2]); p.w = f2bf_rne(o[3]);
            *(ushort4*)(C + (size_t)row * N + bn + 64 * ci + 4 * tx) = p;
          } else {
            float* C = (float*)Cv;
            *(float4*)(C + (size_t)row * N + bn + 64 * ci + 4 * tx) = make_float4(o[0], o[1], o[2], o[3]);
          }
        }
      }
    }
}

// ---------------- aggregation: 128-wide bf16 gather, wave per node ----------------
// 4 edges in flight (g = lane>>4), 8 cols/lane (q = lane&15).

__global__ __launch_bounds__(256) void agg128_kernel(const unsigned short* __restrict__ h,
                                                     const int* __restrict__ rstart, const int* __restrict__ cnt,
                                                     const int2* __restrict__ csr,
                                                     const float* __restrict__ dinv, const float* __restrict__ bias,
                                                     const float* __restrict__ hself, const float* __restrict__ leader,
                                                     float* __restrict__ out, int nnodes) {
  int wave = threadIdx.x >> 6;
  int lane = threadIdx.x & 63;
  int node = blockIdx.x * 4 + wave;
  if (node >= nnodes) return;
  int g = lane >> 4;
  int q = lane & 15;

  float acc[8] = {};
  if (g == 0) {
    float s = dinv[node]; s *= s;
    uint4 v = *(const uint4*)(h + (size_t)node * 128 + 8 * q);
    float f[8]; unpack8(v, f);
#pragma unroll
    for (int j = 0; j < 8; j++) acc[j] = s * f[j];
  }
  int rs = rstart[node];
  int n = cnt[node];
  for (int e = g; e < n; e += 4) {
    int2 en = csr[rs + e];
    float nrm = __int_as_float(en.y);
    uint4 v = *(const uint4*)(h + (size_t)en.x * 128 + 8 * q);
    float f[8]; unpack8(v, f);
#pragma unroll
    for (int j = 0; j < 8; j++) acc[j] += nrm * f[j];
  }
#pragma unroll
  for (int j = 0; j < 8; j++) {
    acc[j] += __shfl_xor(acc[j], 16);
    acc[j] += __shfl_xor(acc[j], 32);
  }

  if (g == 0) {
    float b[8], r[8];
    *(float4*)&b[0] = *(const float4*)(bias + 8 * q);
    *(float4*)&b[4] = *(const float4*)(bias + 8 * q + 4);
#pragma unroll
    for (int j = 0; j < 8; j++) r[j] = fmaxf(acc[j] + b[j], 0.f);
    if (hself) {
      float l = leader[node];
      float hs[8];
      *(float4*)&hs[0] = *(const float4*)(hself + (size_t)node * 128 + 8 * q);
      *(float4*)&hs[4] = *(const float4*)(hself + (size_t)node * 128 + 8 * q + 4);
#pragma unroll
      for (int j = 0; j < 8; j++) r[j] = (1.f - l) * r[j] + l * hs[j];
    }
    *(float4*)(out + (size_t)node * 128 + 8 * q) = *(float4*)&r[0];
    *(float4*)(out + (size_t)node * 128 + 8 * q + 4) = *(float4*)&r[4];
  }
}

// ---------------- aggregation: 64-wide bf16 leader conv + score head ----------------
// 8 edges in flight (g = lane>>3), 8 cols/lane (q = lane&7).

__global__ __launch_bounds__(256) void agg64_leader_kernel(const unsigned short* __restrict__ h,
                                                           const int* __restrict__ rstart, const int* __restrict__ cnt,
                                                           const int2* __restrict__ csr,
                                                           const float* __restrict__ dinv, const float* __restrict__ bl,
                                                           const float* __restrict__ Wl2, const float* __restrict__ bl2,
                                                           float* __restrict__ leader_out, int nnodes) {
  int wave = threadIdx.x >> 6;
  int lane = threadIdx.x & 63;
  int node = blockIdx.x * 4 + wave;
  if (node >= nnodes) return;
  int g = lane >> 3;
  int q = lane & 7;

  float acc[8] = {};
  if (g == 0) {
    float s = dinv[node]; s *= s;
    uint4 v = *(const uint4*)(h + (size_t)node * 64 + 8 * q);
    float f[8]; unpack8(v, f);
#pragma unroll
    for (int j = 0; j < 8; j++) acc[j] = s * f[j];
  }
  int rs = rstart[node];
  int n = cnt[node];
  for (int e = g; e < n; e += 8) {
    int2 en = csr[rs + e];
    float nrm = __int_as_float(en.y);
    uint4 v = *(const uint4*)(h + (size_t)en.x * 64 + 8 * q);
    float f[8]; unpack8(v, f);
#pragma unroll
    for (int j = 0; j < 8; j++) acc[j] += nrm * f[j];
  }
#pragma unroll
  for (int j = 0; j < 8; j++) {
    acc[j] += __shfl_xor(acc[j], 8);
    acc[j] += __shfl_xor(acc[j], 16);
    acc[j] += __shfl_xor(acc[j], 32);
  }

  float b[8], w2[8];
  *(float4*)&b[0] = *(const float4*)(bl + 8 * q);
  *(float4*)&b[4] = *(const float4*)(bl + 8 * q + 4);
  *(float4*)&w2[0] = *(const float4*)(Wl2 + 8 * q);
  *(float4*)&w2[4] = *(const float4*)(Wl2 + 8 * q + 4);
  float part = 0.f;
#pragma unroll
  for (int j = 0; j < 8; j++) part += fmaxf(acc[j] + b[j], 0.f) * w2[j];
  part += __shfl_xor(part, 1);
  part += __shfl_xor(part, 2);
  part += __shfl_xor(part, 4);
  if (lane == 0) {
    float z = part + bl2[0];
    leader_out[node] = 1.f / (1.f + expf(-z));
  }
}

// ---------------- host ----------------

extern "C" void kernel_launch(void* const* d_in, const int* in_sizes, int n_in,
                              void* d_out, int out_size, void* d_ws, size_t ws_size,
                              hipStream_t stream) {
  const float* x   = (const float*)d_in[0];
  const int*   ei  = (const int*)d_in[1];
  const float* ew  = (const float*)d_in[2];
  const float* W1  = (const float*)d_in[3];
  const float* b1  = (const float*)d_in[4];
  const float* W2  = (const float*)d_in[5];
  const float* b2  = (const float*)d_in[6];
  const float* Wsp = (const float*)d_in[7];
  const float* bs  = (const float*)d_in[8];
  const float* Wl  = (const float*)d_in[9];
  const float* bl  = (const float*)d_in[10];
  const float* Wl2 = (const float*)d_in[11];
  const float* bl2 = (const float*)d_in[12];

  const int N = in_sizes[0] / 128;   // 50000
  const int E = in_sizes[1] / 2;     // 800000

  char* ws = (char*)d_ws;
  size_t off = 0;
  auto alloc = [&](size_t bytes) -> void* {
    void* p = ws + off;
    off = (off + bytes + 255) & ~(size_t)255;
    return p;
  };
  float* dinv      = (float*)alloc((size_t)N * 4);
  int*   cnt       = (int*)alloc((size_t)N * 4);
  int*   rstart    = (int*)alloc((size_t)N * 4);
  int*   local_off = (int*)alloc((size_t)E * 4);
  int2*  csr       = (int2*)alloc((size_t)E * 8);
  unsigned short* h1bf = (unsigned short*)alloc((size_t)N * 128 * 2);  // h1, then h2
  unsigned short* hlbf = (unsigned short*)alloc((size_t)N * 64 * 2);
  float* bufC      = (float*)alloc((size_t)N * 128 * 4);  // h_self_proj, then h_new
  int*   bsum      = (int*)alloc(256 * 4);
  int*   bpre      = (int*)alloc(256 * 4);

  float* h_final = (float*)d_out;
  float* leader  = (float*)d_out + (size_t)N * 128;

  int gN = (N + THREADS - 1) / THREADS;
  int gE = (E + THREADS - 1) / THREADS;
  int nScanBlocks = (N + 1023) / 1024;   // 49 <= 64
  int gWave = (N + 3) / 4;

  // graph prep — exactly one atomic per edge
  init_kernel<<<gN, THREADS, 0, stream>>>(cnt, N);
  edge_off_kernel<<<gE, THREADS, 0, stream>>>(ei, cnt, local_off, E);
  scan1_kernel<<<nScanBlocks, 256, 0, stream>>>(cnt, rstart, bsum, N);
  scan2_kernel<<<1, 64, 0, stream>>>(bsum, bpre, nScanBlocks);
  scan3_kernel<<<gN, 256, 0, stream>>>(rstart, bpre, N);
  csr_build_kernel<<<gE, THREADS, 0, stream>>>(ei, ew, rstart, local_off, csr, E);
  deg_wave_kernel<<<gWave, 256, 0, stream>>>(csr, rstart, cnt, dinv, N);
  norm_wave_kernel<<<gWave, 256, 0, stream>>>(csr, rstart, cnt, dinv, N);

  // GEMMs on x: gather-consumed outputs in bf16, gating input in fp32
  int gm = (N + V2_BM - 1) / V2_BM;
  gemm_v2<2, true ><<<dim3(gm, 1), 256, 0, stream>>>(x, W1, nullptr, h1bf, N, 128);  // h1 (bf16)
  gemm_v2<1, true ><<<dim3(gm, 1), 256, 0, stream>>>(x, Wl, nullptr, hlbf, N, 64);   // hl (bf16)
  gemm_v2<2, false><<<dim3(gm, 1), 256, 0, stream>>>(x, Wsp, bs, bufC, N, 128);      // h_self_proj (fp32)

  // leader score
  agg64_leader_kernel<<<gWave, 256, 0, stream>>>(hlbf, rstart, cnt, csr,
                                                 dinv, bl, Wl2, bl2, leader, N);
  // conv1 + relu + gated fusion -> h_new (fp32, overwrites bufC in place)
  agg128_kernel<<<gWave, 256, 0, stream>>>(h1bf, rstart, cnt, csr,
                                           dinv, b1, bufC, leader, bufC, N);
  // h2 = h_new @ W2 (bf16 out, reuse h1bf)
  gemm_v2<2, true><<<dim3(gm, 1), 256, 0, stream>>>(bufC, W2, nullptr, h1bf, N, 128);
  // conv2 + relu -> h_final (fp32)
  agg128_kernel<<<gWave, 256, 0, stream>>>(h1bf, rstart, cnt, csr,
                                           dinv, b2, nullptr, nullptr, h_final, N);
}

// Round 5
// 371.966 us; speedup vs baseline: 1.5396x; 1.0712x over previous
//
#include <hip/hip_runtime.h>
#include <math.h>

#define THREADS 256

typedef unsigned int uint32;
typedef __attribute__((ext_vector_type(8))) short bf16x8;
typedef __attribute__((ext_vector_type(4))) float f32x4;

__device__ __forceinline__ unsigned short f2bf_rne(float x) {
  uint32 u = __float_as_uint(x);
  u += 0x7fffu + ((u >> 16) & 1u);
  return (unsigned short)(u >> 16);
}

__device__ __forceinline__ void unpack8(uint4 v, float* f) {
  f[0] = __uint_as_float(v.x << 16);
  f[1] = __uint_as_float(v.x & 0xffff0000u);
  f[2] = __uint_as_float(v.y << 16);
  f[3] = __uint_as_float(v.y & 0xffff0000u);
  f[4] = __uint_as_float(v.z << 16);
  f[5] = __uint_as_float(v.z & 0xffff0000u);
  f[6] = __uint_as_float(v.w << 16);
  f[7] = __uint_as_float(v.w & 0xffff0000u);
}

// ---------------- setup kernels ----------------

__global__ __launch_bounds__(THREADS) void init_kernel(int* cnt, int n) {
  int i = blockIdx.x * THREADS + threadIdx.x;
  if (i < n) cnt[i] = 0;
}

__global__ __launch_bounds__(THREADS) void edge_off_kernel(const int* __restrict__ ei,
                                                           int* __restrict__ cnt,
                                                           int* __restrict__ local_off, int E) {
  int e = blockIdx.x * THREADS + threadIdx.x;
  if (e >= E) return;
  int d = ei[E + e];
  local_off[e] = atomicAdd(cnt + d, 1);
}

// ---------------- hierarchical exclusive scan of cnt -> rstart ----------------

__global__ __launch_bounds__(256) void scan1_kernel(const int* __restrict__ cnt, int* __restrict__ rstart,
                                                    int* __restrict__ bsum, int n) {
  int t = threadIdx.x;
  int lane = t & 63, wave = t >> 6;
  int base = blockIdx.x * 1024 + t * 4;
  int4 v = make_int4(0, 0, 0, 0);
  if (base + 3 < n) v = *(const int4*)(cnt + base);
  else if (base < n) {
    v.x = cnt[base];
    if (base + 1 < n) v.y = cnt[base + 1];
    if (base + 2 < n) v.z = cnt[base + 2];
  }
  int p1 = v.x, p2 = p1 + v.y, p3 = p2 + v.z, tsum = p3 + v.w;
  int incl = tsum;
#pragma unroll
  for (int off = 1; off < 64; off <<= 1) {
    int u = __shfl_up(incl, off);
    if (lane >= off) incl += u;
  }
  __shared__ int wt[4];
  if (lane == 63) wt[wave] = incl;
  __syncthreads();
  int wadd = 0;
#pragma unroll
  for (int w = 0; w < 4; w++) wadd += (w < wave) ? wt[w] : 0;
  int excl = wadd + incl - tsum;
  if (base < n) {
    rstart[base] = excl;
    if (base + 1 < n) rstart[base + 1] = excl + p1;
    if (base + 2 < n) rstart[base + 2] = excl + p2;
    if (base + 3 < n) rstart[base + 3] = excl + p3;
  }
  if (t == 0) bsum[blockIdx.x] = wt[0] + wt[1] + wt[2] + wt[3];
}

__global__ __launch_bounds__(64) void scan2_kernel(const int* __restrict__ bsum, int* __restrict__ bpre, int nb) {
  int t = threadIdx.x;
  int v = (t < nb) ? bsum[t] : 0;
  int incl = v;
#pragma unroll
  for (int off = 1; off < 64; off <<= 1) {
    int u = __shfl_up(incl, off);
    if (t >= off) incl += u;
  }
  if (t < nb) bpre[t] = incl - v;
}

__global__ __launch_bounds__(256) void scan3_kernel(int* __restrict__ rstart, const int* __restrict__ bpre, int n) {
  int i = blockIdx.x * 256 + threadIdx.x;
  if (i < n) rstart[i] += bpre[i >> 10];
}

// ---------------- CSR build ----------------

__global__ __launch_bounds__(THREADS) void csr_build_kernel(const int* __restrict__ ei, const float* __restrict__ ew,
                                                            const int* __restrict__ rstart, const int* __restrict__ local_off,
                                                            int2* __restrict__ csr, int E) {
  int e = blockIdx.x * THREADS + threadIdx.x;
  if (e >= E) return;
  int s = ei[e];
  int d = ei[E + e];
  int pos = rstart[d] + local_off[e];
  csr[pos] = make_int2(s, __float_as_int(ew[e]));
}

__global__ __launch_bounds__(256) void deg_wave_kernel(const int2* __restrict__ csr,
                                                       const int* __restrict__ rstart, const int* __restrict__ cnt,
                                                       float* __restrict__ dinv, int nnodes) {
  int wave = threadIdx.x >> 6, lane = threadIdx.x & 63;
  int node = blockIdx.x * 4 + wave;
  if (node >= nnodes) return;
  int rs = rstart[node], c = cnt[node];
  float s = 0.f;
  for (int i = lane; i < c; i += 64) s += __int_as_float(csr[rs + i].y);
#pragma unroll
  for (int m = 32; m; m >>= 1) s += __shfl_xor(s, m);
  if (lane == 0) dinv[node] = rsqrtf(1.0f + s);
}

__global__ __launch_bounds__(256) void norm_wave_kernel(int2* __restrict__ csr,
                                                        const int* __restrict__ rstart, const int* __restrict__ cnt,
                                                        const float* __restrict__ dinv, int nnodes) {
  int wave = threadIdx.x >> 6, lane = threadIdx.x & 63;
  int node = blockIdx.x * 4 + wave;
  if (node >= nnodes) return;
  int rs = rstart[node], c = cnt[node];
  float dd = dinv[node];
  for (int i = lane; i < c; i += 64) {
    int2 en = csr[rs + i];
    float w = __int_as_float(en.y);
    csr[rs + i].y = __float_as_int(dinv[en.x] * w * dd);
  }
}

// ---------------- bf16 cast of x ----------------

__global__ __launch_bounds__(256) void cast_bf16_kernel(const float* __restrict__ in,
                                                        unsigned short* __restrict__ out, int n8) {
  int t = blockIdx.x * 256 + threadIdx.x;
  if (t >= n8) return;
  const float* p = in + (size_t)t * 8;
  float4 a = *(const float4*)p;
  float4 b = *(const float4*)(p + 4);
  ushort4 o0, o1;
  o0.x = f2bf_rne(a.x); o0.y = f2bf_rne(a.y); o0.z = f2bf_rne(a.z); o0.w = f2bf_rne(a.w);
  o1.x = f2bf_rne(b.x); o1.y = f2bf_rne(b.y); o1.z = f2bf_rne(b.z); o1.w = f2bf_rne(b.w);
  *(ushort4*)(out + (size_t)t * 8) = o0;
  *(ushort4*)(out + (size_t)t * 8 + 4) = o1;
}

// ---------------- W split: transpose + hi/lo bf16 decomposition ----------------
// slot layout (rows of Wt, each 128 k): [0,128)=W1, [128,192)=Wl, [192,320)=Ws, [320,448)=W2

__global__ __launch_bounds__(256) void wsplit_kernel(const float* __restrict__ W1, const float* __restrict__ Wl,
                                                     const float* __restrict__ Ws, const float* __restrict__ W2,
                                                     unsigned short* __restrict__ whi, unsigned short* __restrict__ wlo) {
  int idx = blockIdx.x * 256 + threadIdx.x;
  if (idx >= 448 * 128) return;
  int slot = idx >> 7;
  int k = idx & 127;
  const float* W; int n, ncols;
  if (slot < 128)      { W = W1; n = slot;       ncols = 128; }
  else if (slot < 192) { W = Wl; n = slot - 128; ncols = 64;  }
  else if (slot < 320) { W = Ws; n = slot - 192; ncols = 128; }
  else                 { W = W2; n = slot - 320; ncols = 128; }
  float v = W[(size_t)k * ncols + n];
  unsigned short hi = f2bf_rne(v);
  float hif = __uint_as_float((uint32)hi << 16);
  unsigned short lo = f2bf_rne(v - hif);
  whi[idx] = hi;
  wlo[idx] = lo;
}

// ---------------- MFMA GEMM: C = A(bf16)[M,128] @ (Whi+Wlo)[128,64-chunk] ----------------
// LDS-free: A-frags and B-frags load 16B contiguous direct from global.
// Block: 256 thr = 4 waves; wave w computes rows [w*32, w*32+32) x 64 cols.

struct Chunk {
  const unsigned short* whi;   // [64 n-rows][128 k] transposed
  const unsigned short* wlo;
  const float* bias;           // nullptr if none (already offset to chunk cols)
  void* out;                   // already offset to chunk col base
  int ostride;
  int obf16;
};
struct GemmArgs { Chunk c[5]; };

__global__ __launch_bounds__(256) void gemm_mfma(const unsigned short* __restrict__ A,
                                                 GemmArgs args, int M) {
  Chunk d = args.c[blockIdx.x];
  int bm = blockIdx.y * 128;
  int w = threadIdx.x >> 6, lane = threadIdx.x & 63;
  int n16 = lane & 15, quad = lane >> 4;

  f32x4 acc[2][4];
#pragma unroll
  for (int rt = 0; rt < 2; rt++)
#pragma unroll
    for (int ct = 0; ct < 4; ct++) acc[rt][ct] = (f32x4){0.f, 0.f, 0.f, 0.f};

  int r0 = bm + w * 32 + n16;
  int r1 = r0 + 16;
  int r0c = r0 < M ? r0 : M - 1;
  int r1c = r1 < M ? r1 : M - 1;
  const unsigned short* a0 = A + (size_t)r0c * 128 + quad * 8;
  const unsigned short* a1 = A + (size_t)r1c * 128 + quad * 8;
  const unsigned short* wh = d.whi + (size_t)n16 * 128 + quad * 8;
  const unsigned short* wl = d.wlo + (size_t)n16 * 128 + quad * 8;

#pragma unroll
  for (int ks = 0; ks < 4; ks++) {
    int ko = ks * 32;
    bf16x8 av0 = *(const bf16x8*)(a0 + ko);
    bf16x8 av1 = *(const bf16x8*)(a1 + ko);
#pragma unroll
    for (int ct = 0; ct < 4; ct++) {
      bf16x8 bh = *(const bf16x8*)(wh + (size_t)ct * 16 * 128 + ko);
      bf16x8 bl = *(const bf16x8*)(wl + (size_t)ct * 16 * 128 + ko);
      acc[0][ct] = __builtin_amdgcn_mfma_f32_16x16x32_bf16(av0, bh, acc[0][ct], 0, 0, 0);
      acc[0][ct] = __builtin_amdgcn_mfma_f32_16x16x32_bf16(av0, bl, acc[0][ct], 0, 0, 0);
      acc[1][ct] = __builtin_amdgcn_mfma_f32_16x16x32_bf16(av1, bh, acc[1][ct], 0, 0, 0);
      acc[1][ct] = __builtin_amdgcn_mfma_f32_16x16x32_bf16(av1, bl, acc[1][ct], 0, 0, 0);
    }
  }

  // epilogue: C/D layout col=lane&15, row=quad*4+reg  [m89-verified]
#pragma unroll
  for (int ct = 0; ct < 4; ct++) {
    int col = ct * 16 + n16;
    float bv = d.bias ? d.bias[col] : 0.f;
#pragma unroll
    for (int rt = 0; rt < 2; rt++) {
#pragma unroll
      for (int reg = 0; reg < 4; reg++) {
        int row = bm + w * 32 + rt * 16 + quad * 4 + reg;
        if (row < M) {
          float v = acc[rt][ct][reg] + bv;
          if (d.obf16)
            ((unsigned short*)d.out)[(size_t)row * d.ostride + col] = f2bf_rne(v);
          else
            ((float*)d.out)[(size_t)row * d.ostride + col] = v;
        }
      }
    }
  }
}

// ---------------- aggregation: 128-wide bf16 gather, wave per node ----------------

__global__ __launch_bounds__(256) void agg128_kernel(const unsigned short* __restrict__ h,
                                                     const int* __restrict__ rstart, const int* __restrict__ cnt,
                                                     const int2* __restrict__ csr,
                                                     const float* __restrict__ dinv, const float* __restrict__ bias,
                                                     const float* __restrict__ hself, const float* __restrict__ leader,
                                                     void* __restrict__ outv, int obf16, int nnodes) {
  int wave = threadIdx.x >> 6;
  int lane = threadIdx.x & 63;
  int node = blockIdx.x * 4 + wave;
  if (node >= nnodes) return;
  int g = lane >> 4;
  int q = lane & 15;

  float acc[8] = {};
  if (g == 0) {
    float s = dinv[node]; s *= s;
    uint4 v = *(const uint4*)(h + (size_t)node * 128 + 8 * q);
    float f[8]; unpack8(v, f);
#pragma unroll
    for (int j = 0; j < 8; j++) acc[j] = s * f[j];
  }
  int rs = rstart[node];
  int n = cnt[node];
  for (int e = g; e < n; e += 4) {
    int2 en = csr[rs + e];
    float nrm = __int_as_float(en.y);
    uint4 v = *(const uint4*)(h + (size_t)en.x * 128 + 8 * q);
    float f[8]; unpack8(v, f);
#pragma unroll
    for (int j = 0; j < 8; j++) acc[j] += nrm * f[j];
  }
#pragma unroll
  for (int j = 0; j < 8; j++) {
    acc[j] += __shfl_xor(acc[j], 16);
    acc[j] += __shfl_xor(acc[j], 32);
  }

  if (g == 0) {
    float b[8], r[8];
    *(float4*)&b[0] = *(const float4*)(bias + 8 * q);
    *(float4*)&b[4] = *(const float4*)(bias + 8 * q + 4);
#pragma unroll
    for (int j = 0; j < 8; j++) r[j] = fmaxf(acc[j] + b[j], 0.f);
    if (hself) {
      float l = leader[node];
      float hs[8];
      *(float4*)&hs[0] = *(const float4*)(hself + (size_t)node * 128 + 8 * q);
      *(float4*)&hs[4] = *(const float4*)(hself + (size_t)node * 128 + 8 * q + 4);
#pragma unroll
      for (int j = 0; j < 8; j++) r[j] = (1.f - l) * r[j] + l * hs[j];
    }
    if (obf16) {
      unsigned short* out = (unsigned short*)outv;
      ushort4 p0, p1;
      p0.x = f2bf_rne(r[0]); p0.y = f2bf_rne(r[1]); p0.z = f2bf_rne(r[2]); p0.w = f2bf_rne(r[3]);
      p1.x = f2bf_rne(r[4]); p1.y = f2bf_rne(r[5]); p1.z = f2bf_rne(r[6]); p1.w = f2bf_rne(r[7]);
      *(ushort4*)(out + (size_t)node * 128 + 8 * q) = p0;
      *(ushort4*)(out + (size_t)node * 128 + 8 * q + 4) = p1;
    } else {
      float* out = (float*)outv;
      *(float4*)(out + (size_t)node * 128 + 8 * q) = *(float4*)&r[0];
      *(float4*)(out + (size_t)node * 128 + 8 * q + 4) = *(float4*)&r[4];
    }
  }
}

// ---------------- aggregation: 64-wide bf16 leader conv + score head ----------------

__global__ __launch_bounds__(256) void agg64_leader_kernel(const unsigned short* __restrict__ h,
                                                           const int* __restrict__ rstart, const int* __restrict__ cnt,
                                                           const int2* __restrict__ csr,
                                                           const float* __restrict__ dinv, const float* __restrict__ bl,
                                                           const float* __restrict__ Wl2, const float* __restrict__ bl2,
                                                           float* __restrict__ leader_out, int nnodes) {
  int wave = threadIdx.x >> 6;
  int lane = threadIdx.x & 63;
  int node = blockIdx.x * 4 + wave;
  if (node >= nnodes) return;
  int g = lane >> 3;
  int q = lane & 7;

  float acc[8] = {};
  if (g == 0) {
    float s = dinv[node]; s *= s;
    uint4 v = *(const uint4*)(h + (size_t)node * 64 + 8 * q);
    float f[8]; unpack8(v, f);
#pragma unroll
    for (int j = 0; j < 8; j++) acc[j] = s * f[j];
  }
  int rs = rstart[node];
  int n = cnt[node];
  for (int e = g; e < n; e += 8) {
    int2 en = csr[rs + e];
    float nrm = __int_as_float(en.y);
    uint4 v = *(const uint4*)(h + (size_t)en.x * 64 + 8 * q);
    float f[8]; unpack8(v, f);
#pragma unroll
    for (int j = 0; j < 8; j++) acc[j] += nrm * f[j];
  }
#pragma unroll
  for (int j = 0; j < 8; j++) {
    acc[j] += __shfl_xor(acc[j], 8);
    acc[j] += __shfl_xor(acc[j], 16);
    acc[j] += __shfl_xor(acc[j], 32);
  }

  float b[8], w2[8];
  *(float4*)&b[0] = *(const float4*)(bl + 8 * q);
  *(float4*)&b[4] = *(const float4*)(bl + 8 * q + 4);
  *(float4*)&w2[0] = *(const float4*)(Wl2 + 8 * q);
  *(float4*)&w2[4] = *(const float4*)(Wl2 + 8 * q + 4);
  float part = 0.f;
#pragma unroll
  for (int j = 0; j < 8; j++) part += fmaxf(acc[j] + b[j], 0.f) * w2[j];
  part += __shfl_xor(part, 1);
  part += __shfl_xor(part, 2);
  part += __shfl_xor(part, 4);
  if (lane == 0) {
    float z = part + bl2[0];
    leader_out[node] = 1.f / (1.f + expf(-z));
  }
}

// ---------------- host ----------------

extern "C" void kernel_launch(void* const* d_in, const int* in_sizes, int n_in,
                              void* d_out, int out_size, void* d_ws, size_t ws_size,
                              hipStream_t stream) {
  const float* x   = (const float*)d_in[0];
  const int*   ei  = (const int*)d_in[1];
  const float* ew  = (const float*)d_in[2];
  const float* W1  = (const float*)d_in[3];
  const float* b1  = (const float*)d_in[4];
  const float* W2  = (const float*)d_in[5];
  const float* b2  = (const float*)d_in[6];
  const float* Wsp = (const float*)d_in[7];
  const float* bs  = (const float*)d_in[8];
  const float* Wl  = (const float*)d_in[9];
  const float* bl  = (const float*)d_in[10];
  const float* Wl2 = (const float*)d_in[11];
  const float* bl2 = (const float*)d_in[12];

  const int N = in_sizes[0] / 128;   // 50000
  const int E = in_sizes[1] / 2;     // 800000

  char* ws = (char*)d_ws;
  size_t off = 0;
  auto alloc = [&](size_t bytes) -> void* {
    void* p = ws + off;
    off = (off + bytes + 255) & ~(size_t)255;
    return p;
  };
  float* dinv      = (float*)alloc((size_t)N * 4);
  int*   cnt       = (int*)alloc((size_t)N * 4);
  int*   rstart    = (int*)alloc((size_t)N * 4);
  int*   local_off = (int*)alloc((size_t)E * 4);
  int2*  csr       = (int2*)alloc((size_t)E * 8);
  unsigned short* xbf    = (unsigned short*)alloc((size_t)N * 128 * 2);
  unsigned short* h1bf   = (unsigned short*)alloc((size_t)N * 128 * 2);  // h1, then h2
  unsigned short* hlbf   = (unsigned short*)alloc((size_t)N * 64 * 2);
  unsigned short* hnewbf = (unsigned short*)alloc((size_t)N * 128 * 2);
  float* bufC      = (float*)alloc((size_t)N * 128 * 4);  // h_self_proj (fp32)
  unsigned short* whi = (unsigned short*)alloc((size_t)448 * 128 * 2);
  unsigned short* wlo = (unsigned short*)alloc((size_t)448 * 128 * 2);
  int*   bsum      = (int*)alloc(256 * 4);
  int*   bpre      = (int*)alloc(256 * 4);

  float* h_final = (float*)d_out;
  float* leader  = (float*)d_out + (size_t)N * 128;

  int gN = (N + THREADS - 1) / THREADS;
  int gE = (E + THREADS - 1) / THREADS;
  int nScanBlocks = (N + 1023) / 1024;   // 49 <= 64
  int gWave = (N + 3) / 4;
  int gmRows = (N + 127) / 128;          // 391

  // graph prep — exactly one atomic per edge
  init_kernel<<<gN, THREADS, 0, stream>>>(cnt, N);
  edge_off_kernel<<<gE, THREADS, 0, stream>>>(ei, cnt, local_off, E);
  scan1_kernel<<<nScanBlocks, 256, 0, stream>>>(cnt, rstart, bsum, N);
  scan2_kernel<<<1, 64, 0, stream>>>(bsum, bpre, nScanBlocks);
  scan3_kernel<<<gN, 256, 0, stream>>>(rstart, bpre, N);
  csr_build_kernel<<<gE, THREADS, 0, stream>>>(ei, ew, rstart, local_off, csr, E);
  deg_wave_kernel<<<gWave, 256, 0, stream>>>(csr, rstart, cnt, dinv, N);
  norm_wave_kernel<<<gWave, 256, 0, stream>>>(csr, rstart, cnt, dinv, N);

  // weight split + x cast
  wsplit_kernel<<<(448 * 128 + 255) / 256, 256, 0, stream>>>(W1, Wl, Wsp, W2, whi, wlo);
  cast_bf16_kernel<<<(N * 16 + 255) / 256, 256, 0, stream>>>(x, xbf, N * 16);

  // fused x-GEMMs: h1 = x@W1 (bf16), hl = x@Wl (bf16), hsp = x@Ws + bs (fp32)
  {
    GemmArgs ga;
    ga.c[0] = {whi + 0 * 128,   wlo + 0 * 128,   nullptr, h1bf,      128, 1};  // W1 cols 0-63
    ga.c[1] = {whi + 64 * 128,  wlo + 64 * 128,  nullptr, h1bf + 64, 128, 1};  // W1 cols 64-127
    ga.c[2] = {whi + 128 * 128, wlo + 128 * 128, nullptr, hlbf,      64,  1};  // Wl cols 0-63
    ga.c[3] = {whi + 192 * 128, wlo + 192 * 128, bs,      bufC,      128, 0};  // Ws cols 0-63
    ga.c[4] = {whi + 256 * 128, wlo + 256 * 128, bs + 64, bufC + 64, 128, 0};  // Ws cols 64-127
    gemm_mfma<<<dim3(5, gmRows), 256, 0, stream>>>(xbf, ga, N);
  }

  // leader score
  agg64_leader_kernel<<<gWave, 256, 0, stream>>>(hlbf, rstart, cnt, csr,
                                                 dinv, bl, Wl2, bl2, leader, N);
  // conv1 + relu + gated fusion -> h_new (bf16 directly)
  agg128_kernel<<<gWave, 256, 0, stream>>>(h1bf, rstart, cnt, csr,
                                           dinv, b1, bufC, leader, hnewbf, 1, N);
  // h2 = h_new @ W2 (bf16 out, reuse h1bf)
  {
    GemmArgs ga;
    ga.c[0] = {whi + 320 * 128, wlo + 320 * 128, nullptr, h1bf,      128, 1};
    ga.c[1] = {whi + 384 * 128, wlo + 384 * 128, nullptr, h1bf + 64, 128, 1};
    ga.c[2] = ga.c[0]; ga.c[3] = ga.c[0]; ga.c[4] = ga.c[0];
    gemm_mfma<<<dim3(2, gmRows), 256, 0, stream>>>(hnewbf, ga, N);
  }
  // conv2 + relu -> h_final (fp32)
  agg128_kernel<<<gWave, 256, 0, stream>>>(h1bf, rstart, cnt, csr,
                                           dinv, b2, nullptr, nullptr, h_final, 0, N);
}

// Round 6
// 346.275 us; speedup vs baseline: 1.6538x; 1.0742x over previous
//
#include <hip/hip_runtime.h>
#include <math.h>

#define THREADS 256

typedef unsigned int uint32;
typedef __attribute__((ext_vector_type(8))) short bf16x8;
typedef __attribute__((ext_vector_type(4))) float f32x4;

__device__ __forceinline__ unsigned short f2bf_rne(float x) {
  uint32 u = __float_as_uint(x);
  u += 0x7fffu + ((u >> 16) & 1u);
  return (unsigned short)(u >> 16);
}

__device__ __forceinline__ void unpack8(uint4 v, float* f) {
  f[0] = __uint_as_float(v.x << 16);
  f[1] = __uint_as_float(v.x & 0xffff0000u);
  f[2] = __uint_as_float(v.y << 16);
  f[3] = __uint_as_float(v.y & 0xffff0000u);
  f[4] = __uint_as_float(v.z << 16);
  f[5] = __uint_as_float(v.z & 0xffff0000u);
  f[6] = __uint_as_float(v.w << 16);
  f[7] = __uint_as_float(v.w & 0xffff0000u);
}

// ---------------- setup kernels ----------------

__global__ __launch_bounds__(THREADS) void init_kernel(int* cnt, int n) {
  int i = blockIdx.x * THREADS + threadIdx.x;
  if (i < n) cnt[i] = 0;
}

__global__ __launch_bounds__(THREADS) void edge_off_kernel(const int* __restrict__ ei,
                                                           int* __restrict__ cnt,
                                                           int* __restrict__ local_off, int E) {
  int e = blockIdx.x * THREADS + threadIdx.x;
  if (e >= E) return;
  int d = ei[E + e];
  local_off[e] = atomicAdd(cnt + d, 1);
}

// ---------------- hierarchical exclusive scan of cnt -> rstart ----------------

__global__ __launch_bounds__(256) void scan1_kernel(const int* __restrict__ cnt, int* __restrict__ rstart,
                                                    int* __restrict__ bsum, int n) {
  int t = threadIdx.x;
  int lane = t & 63, wave = t >> 6;
  int base = blockIdx.x * 1024 + t * 4;
  int4 v = make_int4(0, 0, 0, 0);
  if (base + 3 < n) v = *(const int4*)(cnt + base);
  else if (base < n) {
    v.x = cnt[base];
    if (base + 1 < n) v.y = cnt[base + 1];
    if (base + 2 < n) v.z = cnt[base + 2];
  }
  int p1 = v.x, p2 = p1 + v.y, p3 = p2 + v.z, tsum = p3 + v.w;
  int incl = tsum;
#pragma unroll
  for (int off = 1; off < 64; off <<= 1) {
    int u = __shfl_up(incl, off);
    if (lane >= off) incl += u;
  }
  __shared__ int wt[4];
  if (lane == 63) wt[wave] = incl;
  __syncthreads();
  int wadd = 0;
#pragma unroll
  for (int w = 0; w < 4; w++) wadd += (w < wave) ? wt[w] : 0;
  int excl = wadd + incl - tsum;
  if (base < n) {
    rstart[base] = excl;
    if (base + 1 < n) rstart[base + 1] = excl + p1;
    if (base + 2 < n) rstart[base + 2] = excl + p2;
    if (base + 3 < n) rstart[base + 3] = excl + p3;
  }
  if (t == 0) bsum[blockIdx.x] = wt[0] + wt[1] + wt[2] + wt[3];
}

__global__ __launch_bounds__(64) void scan2_kernel(const int* __restrict__ bsum, int* __restrict__ bpre, int nb) {
  int t = threadIdx.x;
  int v = (t < nb) ? bsum[t] : 0;
  int incl = v;
#pragma unroll
  for (int off = 1; off < 64; off <<= 1) {
    int u = __shfl_up(incl, off);
    if (t >= off) incl += u;
  }
  if (t < nb) bpre[t] = incl - v;
}

__global__ __launch_bounds__(256) void scan3_kernel(int* __restrict__ rstart, const int* __restrict__ bpre, int n) {
  int i = blockIdx.x * 256 + threadIdx.x;
  if (i < n) rstart[i] += bpre[i >> 10];
}

// ---------------- CSR build ----------------

__global__ __launch_bounds__(THREADS) void csr_build_kernel(const int* __restrict__ ei, const float* __restrict__ ew,
                                                            const int* __restrict__ rstart, const int* __restrict__ local_off,
                                                            int2* __restrict__ csr, int E) {
  int e = blockIdx.x * THREADS + threadIdx.x;
  if (e >= E) return;
  int s = ei[e];
  int d = ei[E + e];
  int pos = rstart[d] + local_off[e];
  csr[pos] = make_int2(s, __float_as_int(ew[e]));
}

__global__ __launch_bounds__(256) void deg_wave_kernel(const int2* __restrict__ csr,
                                                       const int* __restrict__ rstart, const int* __restrict__ cnt,
                                                       float* __restrict__ dinv, int nnodes) {
  int wave = threadIdx.x >> 6, lane = threadIdx.x & 63;
  int node = blockIdx.x * 4 + wave;
  if (node >= nnodes) return;
  int rs = rstart[node], c = cnt[node];
  float s = 0.f;
  for (int i = lane; i < c; i += 64) s += __int_as_float(csr[rs + i].y);
#pragma unroll
  for (int m = 32; m; m >>= 1) s += __shfl_xor(s, m);
  if (lane == 0) dinv[node] = rsqrtf(1.0f + s);
}

__global__ __launch_bounds__(256) void norm_wave_kernel(int2* __restrict__ csr,
                                                        const int* __restrict__ rstart, const int* __restrict__ cnt,
                                                        const float* __restrict__ dinv, int nnodes) {
  int wave = threadIdx.x >> 6, lane = threadIdx.x & 63;
  int node = blockIdx.x * 4 + wave;
  if (node >= nnodes) return;
  int rs = rstart[node], c = cnt[node];
  float dd = dinv[node];
  for (int i = lane; i < c; i += 64) {
    int2 en = csr[rs + i];
    float w = __int_as_float(en.y);
    csr[rs + i].y = __float_as_int(dinv[en.x] * w * dd);
  }
}

// ---------------- bf16 cast of x ----------------

__global__ __launch_bounds__(256) void cast_bf16_kernel(const float* __restrict__ in,
                                                        unsigned short* __restrict__ out, int n8) {
  int t = blockIdx.x * 256 + threadIdx.x;
  if (t >= n8) return;
  const float* p = in + (size_t)t * 8;
  float4 a = *(const float4*)p;
  float4 b = *(const float4*)(p + 4);
  ushort4 o0, o1;
  o0.x = f2bf_rne(a.x); o0.y = f2bf_rne(a.y); o0.z = f2bf_rne(a.z); o0.w = f2bf_rne(a.w);
  o1.x = f2bf_rne(b.x); o1.y = f2bf_rne(b.y); o1.z = f2bf_rne(b.z); o1.w = f2bf_rne(b.w);
  *(ushort4*)(out + (size_t)t * 8) = o0;
  *(ushort4*)(out + (size_t)t * 8 + 4) = o1;
}

// ---------------- W split: transpose + hi/lo bf16 decomposition ----------------
// slot layout (rows of Wt, each 128 k): [0,128)=W1, [128,192)=Wl, [192,320)=Ws, [320,448)=W2

__global__ __launch_bounds__(256) void wsplit_kernel(const float* __restrict__ W1, const float* __restrict__ Wl,
                                                     const float* __restrict__ Ws, const float* __restrict__ W2,
                                                     unsigned short* __restrict__ whi, unsigned short* __restrict__ wlo) {
  int idx = blockIdx.x * 256 + threadIdx.x;
  if (idx >= 448 * 128) return;
  int slot = idx >> 7;
  int k = idx & 127;
  const float* W; int n, ncols;
  if (slot < 128)      { W = W1; n = slot;       ncols = 128; }
  else if (slot < 192) { W = Wl; n = slot - 128; ncols = 64;  }
  else if (slot < 320) { W = Ws; n = slot - 192; ncols = 128; }
  else                 { W = W2; n = slot - 320; ncols = 128; }
  float v = W[(size_t)k * ncols + n];
  unsigned short hi = f2bf_rne(v);
  float hif = __uint_as_float((uint32)hi << 16);
  unsigned short lo = f2bf_rne(v - hif);
  whi[idx] = hi;
  wlo[idx] = lo;
}

// ---------------- MFMA GEMM v3: B-fragments resident in registers ----------------
// grid (nchunk, R); each block loads its chunk's W frags (hi+lo) once, then
// grid-strides over 128-row tiles: 8 A-loads + 64 MFMA + stores per tile.

struct Chunk {
  const unsigned short* whi;   // [64 n-rows][128 k] transposed
  const unsigned short* wlo;
  const float* bias;           // pre-offset to chunk cols, or nullptr
  void* out;                   // pre-offset to chunk col base
  int ostride;
  int obf16;
};
struct GemmArgs { Chunk c[5]; };

__global__ __launch_bounds__(256, 2) void gemm_v3(const unsigned short* __restrict__ A,
                                                  GemmArgs args, int M, int nTiles) {
  Chunk d = args.c[blockIdx.x];
  int w = threadIdx.x >> 6, lane = threadIdx.x & 63;
  int n16 = lane & 15, quad = lane >> 4;

  // B fragments: [ct][ks] for hi and lo — loaded once, live in VGPRs (128)
  bf16x8 Bh[4][4], Bl[4][4];
  {
    const unsigned short* wh = d.whi + (size_t)n16 * 128 + quad * 8;
    const unsigned short* wl = d.wlo + (size_t)n16 * 128 + quad * 8;
#pragma unroll
    for (int ct = 0; ct < 4; ct++)
#pragma unroll
      for (int ks = 0; ks < 4; ks++) {
        Bh[ct][ks] = *(const bf16x8*)(wh + ct * 16 * 128 + ks * 32);
        Bl[ct][ks] = *(const bf16x8*)(wl + ct * 16 * 128 + ks * 32);
      }
  }
  float bv[4];
#pragma unroll
  for (int ct = 0; ct < 4; ct++) bv[ct] = d.bias ? d.bias[ct * 16 + n16] : 0.f;

  for (int tile = blockIdx.y; tile < nTiles; tile += gridDim.y) {
    int bm = tile * 128;
    int r0 = bm + w * 32 + n16;
    int r1 = r0 + 16;
    int r0c = r0 < M ? r0 : M - 1;
    int r1c = r1 < M ? r1 : M - 1;
    const unsigned short* a0 = A + (size_t)r0c * 128 + quad * 8;
    const unsigned short* a1 = A + (size_t)r1c * 128 + quad * 8;
    bf16x8 av0[4], av1[4];
#pragma unroll
    for (int ks = 0; ks < 4; ks++) {
      av0[ks] = *(const bf16x8*)(a0 + ks * 32);
      av1[ks] = *(const bf16x8*)(a1 + ks * 32);
    }

    f32x4 acc[2][4];
#pragma unroll
    for (int rt = 0; rt < 2; rt++)
#pragma unroll
      for (int ct = 0; ct < 4; ct++) acc[rt][ct] = (f32x4){0.f, 0.f, 0.f, 0.f};

#pragma unroll
    for (int ks = 0; ks < 4; ks++)
#pragma unroll
      for (int ct = 0; ct < 4; ct++) {
        acc[0][ct] = __builtin_amdgcn_mfma_f32_16x16x32_bf16(av0[ks], Bh[ct][ks], acc[0][ct], 0, 0, 0);
        acc[0][ct] = __builtin_amdgcn_mfma_f32_16x16x32_bf16(av0[ks], Bl[ct][ks], acc[0][ct], 0, 0, 0);
        acc[1][ct] = __builtin_amdgcn_mfma_f32_16x16x32_bf16(av1[ks], Bh[ct][ks], acc[1][ct], 0, 0, 0);
        acc[1][ct] = __builtin_amdgcn_mfma_f32_16x16x32_bf16(av1[ks], Bl[ct][ks], acc[1][ct], 0, 0, 0);
      }

    // epilogue: C/D layout col=lane&15, row=quad*4+reg  [m89-verified]
#pragma unroll
    for (int ct = 0; ct < 4; ct++) {
      int col = ct * 16 + n16;
#pragma unroll
      for (int rt = 0; rt < 2; rt++) {
#pragma unroll
        for (int reg = 0; reg < 4; reg++) {
          int row = bm + w * 32 + rt * 16 + quad * 4 + reg;
          if (row < M) {
            float v = acc[rt][ct][reg] + bv[ct];
            if (d.obf16)
              ((unsigned short*)d.out)[(size_t)row * d.ostride + col] = f2bf_rne(v);
            else
              ((float*)d.out)[(size_t)row * d.ostride + col] = v;
          }
        }
      }
    }
  }
}

// ---------------- aggregation: 128-wide bf16 gather, wave per node ----------------

__global__ __launch_bounds__(256) void agg128_kernel(const unsigned short* __restrict__ h,
                                                     const int* __restrict__ rstart, const int* __restrict__ cnt,
                                                     const int2* __restrict__ csr,
                                                     const float* __restrict__ dinv, const float* __restrict__ bias,
                                                     const float* __restrict__ hself, const float* __restrict__ leader,
                                                     void* __restrict__ outv, int obf16, int nnodes) {
  int wave = threadIdx.x >> 6;
  int lane = threadIdx.x & 63;
  int node = blockIdx.x * 4 + wave;
  if (node >= nnodes) return;
  int g = lane >> 4;
  int q = lane & 15;

  float acc[8] = {};
  if (g == 0) {
    float s = dinv[node]; s *= s;
    uint4 v = *(const uint4*)(h + (size_t)node * 128 + 8 * q);
    float f[8]; unpack8(v, f);
#pragma unroll
    for (int j = 0; j < 8; j++) acc[j] = s * f[j];
  }
  int rs = rstart[node];
  int n = cnt[node];
  for (int e = g; e < n; e += 4) {
    int2 en = csr[rs + e];
    float nrm = __int_as_float(en.y);
    uint4 v = *(const uint4*)(h + (size_t)en.x * 128 + 8 * q);
    float f[8]; unpack8(v, f);
#pragma unroll
    for (int j = 0; j < 8; j++) acc[j] += nrm * f[j];
  }
#pragma unroll
  for (int j = 0; j < 8; j++) {
    acc[j] += __shfl_xor(acc[j], 16);
    acc[j] += __shfl_xor(acc[j], 32);
  }

  if (g == 0) {
    float b[8], r[8];
    *(float4*)&b[0] = *(const float4*)(bias + 8 * q);
    *(float4*)&b[4] = *(const float4*)(bias + 8 * q + 4);
#pragma unroll
    for (int j = 0; j < 8; j++) r[j] = fmaxf(acc[j] + b[j], 0.f);
    if (hself) {
      float l = leader[node];
      float hs[8];
      *(float4*)&hs[0] = *(const float4*)(hself + (size_t)node * 128 + 8 * q);
      *(float4*)&hs[4] = *(const float4*)(hself + (size_t)node * 128 + 8 * q + 4);
#pragma unroll
      for (int j = 0; j < 8; j++) r[j] = (1.f - l) * r[j] + l * hs[j];
    }
    if (obf16) {
      unsigned short* out = (unsigned short*)outv;
      ushort4 p0, p1;
      p0.x = f2bf_rne(r[0]); p0.y = f2bf_rne(r[1]); p0.z = f2bf_rne(r[2]); p0.w = f2bf_rne(r[3]);
      p1.x = f2bf_rne(r[4]); p1.y = f2bf_rne(r[5]); p1.z = f2bf_rne(r[6]); p1.w = f2bf_rne(r[7]);
      *(ushort4*)(out + (size_t)node * 128 + 8 * q) = p0;
      *(ushort4*)(out + (size_t)node * 128 + 8 * q + 4) = p1;
    } else {
      float* out = (float*)outv;
      *(float4*)(out + (size_t)node * 128 + 8 * q) = *(float4*)&r[0];
      *(float4*)(out + (size_t)node * 128 + 8 * q + 4) = *(float4*)&r[4];
    }
  }
}

// ---------------- aggregation: 64-wide bf16 leader conv + score head ----------------

__global__ __launch_bounds__(256) void agg64_leader_kernel(const unsigned short* __restrict__ h,
                                                           const int* __restrict__ rstart, const int* __restrict__ cnt,
                                                           const int2* __restrict__ csr,
                                                           const float* __restrict__ dinv, const float* __restrict__ bl,
                                                           const float* __restrict__ Wl2, const float* __restrict__ bl2,
                                                           float* __restrict__ leader_out, int nnodes) {
  int wave = threadIdx.x >> 6;
  int lane = threadIdx.x & 63;
  int node = blockIdx.x * 4 + wave;
  if (node >= nnodes) return;
  int g = lane >> 3;
  int q = lane & 7;

  float acc[8] = {};
  if (g == 0) {
    float s = dinv[node]; s *= s;
    uint4 v = *(const uint4*)(h + (size_t)node * 64 + 8 * q);
    float f[8]; unpack8(v, f);
#pragma unroll
    for (int j = 0; j < 8; j++) acc[j] = s * f[j];
  }
  int rs = rstart[node];
  int n = cnt[node];
  for (int e = g; e < n; e += 8) {
    int2 en = csr[rs + e];
    float nrm = __int_as_float(en.y);
    uint4 v = *(const uint4*)(h + (size_t)en.x * 64 + 8 * q);
    float f[8]; unpack8(v, f);
#pragma unroll
    for (int j = 0; j < 8; j++) acc[j] += nrm * f[j];
  }
#pragma unroll
  for (int j = 0; j < 8; j++) {
    acc[j] += __shfl_xor(acc[j], 8);
    acc[j] += __shfl_xor(acc[j], 16);
    acc[j] += __shfl_xor(acc[j], 32);
  }

  float b[8], w2[8];
  *(float4*)&b[0] = *(const float4*)(bl + 8 * q);
  *(float4*)&b[4] = *(const float4*)(bl + 8 * q + 4);
  *(float4*)&w2[0] = *(const float4*)(Wl2 + 8 * q);
  *(float4*)&w2[4] = *(const float4*)(Wl2 + 8 * q + 4);
  float part = 0.f;
#pragma unroll
  for (int j = 0; j < 8; j++) part += fmaxf(acc[j] + b[j], 0.f) * w2[j];
  part += __shfl_xor(part, 1);
  part += __shfl_xor(part, 2);
  part += __shfl_xor(part, 4);
  if (lane == 0) {
    float z = part + bl2[0];
    leader_out[node] = 1.f / (1.f + expf(-z));
  }
}

// ---------------- host ----------------

extern "C" void kernel_launch(void* const* d_in, const int* in_sizes, int n_in,
                              void* d_out, int out_size, void* d_ws, size_t ws_size,
                              hipStream_t stream) {
  const float* x   = (const float*)d_in[0];
  const int*   ei  = (const int*)d_in[1];
  const float* ew  = (const float*)d_in[2];
  const float* W1  = (const float*)d_in[3];
  const float* b1  = (const float*)d_in[4];
  const float* W2  = (const float*)d_in[5];
  const float* b2  = (const float*)d_in[6];
  const float* Wsp = (const float*)d_in[7];
  const float* bs  = (const float*)d_in[8];
  const float* Wl  = (const float*)d_in[9];
  const float* bl  = (const float*)d_in[10];
  const float* Wl2 = (const float*)d_in[11];
  const float* bl2 = (const float*)d_in[12];

  const int N = in_sizes[0] / 128;   // 50000
  const int E = in_sizes[1] / 2;     // 800000

  char* ws = (char*)d_ws;
  size_t off = 0;
  auto alloc = [&](size_t bytes) -> void* {
    void* p = ws + off;
    off = (off + bytes + 255) & ~(size_t)255;
    return p;
  };
  float* dinv      = (float*)alloc((size_t)N * 4);
  int*   cnt       = (int*)alloc((size_t)N * 4);
  int*   rstart    = (int*)alloc((size_t)N * 4);
  int*   local_off = (int*)alloc((size_t)E * 4);
  int2*  csr       = (int2*)alloc((size_t)E * 8);
  unsigned short* xbf    = (unsigned short*)alloc((size_t)N * 128 * 2);
  unsigned short* h1bf   = (unsigned short*)alloc((size_t)N * 128 * 2);  // h1, then h2
  unsigned short* hlbf   = (unsigned short*)alloc((size_t)N * 64 * 2);
  unsigned short* hnewbf = (unsigned short*)alloc((size_t)N * 128 * 2);
  float* bufC      = (float*)alloc((size_t)N * 128 * 4);  // h_self_proj (fp32)
  unsigned short* whi = (unsigned short*)alloc((size_t)448 * 128 * 2);
  unsigned short* wlo = (unsigned short*)alloc((size_t)448 * 128 * 2);
  int*   bsum      = (int*)alloc(256 * 4);
  int*   bpre      = (int*)alloc(256 * 4);

  float* h_final = (float*)d_out;
  float* leader  = (float*)d_out + (size_t)N * 128;

  int gN = (N + THREADS - 1) / THREADS;
  int gE = (E + THREADS - 1) / THREADS;
  int nScanBlocks = (N + 1023) / 1024;   // 49 <= 64
  int gWave = (N + 3) / 4;
  int nTiles = (N + 127) / 128;          // 391

  // graph prep — exactly one atomic per edge
  init_kernel<<<gN, THREADS, 0, stream>>>(cnt, N);
  edge_off_kernel<<<gE, THREADS, 0, stream>>>(ei, cnt, local_off, E);
  scan1_kernel<<<nScanBlocks, 256, 0, stream>>>(cnt, rstart, bsum, N);
  scan2_kernel<<<1, 64, 0, stream>>>(bsum, bpre, nScanBlocks);
  scan3_kernel<<<gN, 256, 0, stream>>>(rstart, bpre, N);
  csr_build_kernel<<<gE, THREADS, 0, stream>>>(ei, ew, rstart, local_off, csr, E);
  deg_wave_kernel<<<gWave, 256, 0, stream>>>(csr, rstart, cnt, dinv, N);
  norm_wave_kernel<<<gWave, 256, 0, stream>>>(csr, rstart, cnt, dinv, N);

  // weight split + x cast
  wsplit_kernel<<<(448 * 128 + 255) / 256, 256, 0, stream>>>(W1, Wl, Wsp, W2, whi, wlo);
  cast_bf16_kernel<<<(N * 16 + 255) / 256, 256, 0, stream>>>(x, xbf, N * 16);

  // fused x-GEMMs: h1 = x@W1 (bf16), hl = x@Wl (bf16), hsp = x@Ws + bs (fp32)
  {
    GemmArgs ga;
    ga.c[0] = {whi + 0 * 128,   wlo + 0 * 128,   nullptr, h1bf,      128, 1};  // W1 cols 0-63
    ga.c[1] = {whi + 64 * 128,  wlo + 64 * 128,  nullptr, h1bf + 64, 128, 1};  // W1 cols 64-127
    ga.c[2] = {whi + 128 * 128, wlo + 128 * 128, nullptr, hlbf,      64,  1};  // Wl cols 0-63
    ga.c[3] = {whi + 192 * 128, wlo + 192 * 128, bs,      bufC,      128, 0};  // Ws cols 0-63
    ga.c[4] = {whi + 256 * 128, wlo + 256 * 128, bs + 64, bufC + 64, 128, 0};  // Ws cols 64-127
    gemm_v3<<<dim3(5, 104), 256, 0, stream>>>(xbf, ga, N, nTiles);
  }

  // leader score
  agg64_leader_kernel<<<gWave, 256, 0, stream>>>(hlbf, rstart, cnt, csr,
                                                 dinv, bl, Wl2, bl2, leader, N);
  // conv1 + relu + gated fusion -> h_new (bf16 directly)
  agg128_kernel<<<gWave, 256, 0, stream>>>(h1bf, rstart, cnt, csr,
                                           dinv, b1, bufC, leader, hnewbf, 1, N);
  // h2 = h_new @ W2 (bf16 out, reuse h1bf)
  {
    GemmArgs ga;
    ga.c[0] = {whi + 320 * 128, wlo + 320 * 128, nullptr, h1bf,      128, 1};
    ga.c[1] = {whi + 384 * 128, wlo + 384 * 128, nullptr, h1bf + 64, 128, 1};
    ga.c[2] = ga.c[0]; ga.c[3] = ga.c[0]; ga.c[4] = ga.c[0];
    gemm_v3<<<dim3(2, 256), 256, 0, stream>>>(hnewbf, ga, N, nTiles);
  }
  // conv2 + relu -> h_final (fp32)
  agg128_kernel<<<gWave, 256, 0, stream>>>(h1bf, rstart, cnt, csr,
                                           dinv, b2, nullptr, nullptr, h_final, 0, N);
}

// Round 7
// 317.649 us; speedup vs baseline: 1.8028x; 1.0901x over previous
//
#include <hip/hip_runtime.h>
#include <math.h>

#define THREADS 256

typedef unsigned int uint32;
typedef __attribute__((ext_vector_type(8))) short bf16x8;
typedef __attribute__((ext_vector_type(4))) float f32x4;

__device__ __forceinline__ unsigned short f2bf_rne(float x) {
  uint32 u = __float_as_uint(x);
  u += 0x7fffu + ((u >> 16) & 1u);
  return (unsigned short)(u >> 16);
}

__device__ __forceinline__ void unpack8(uint4 v, float* f) {
  f[0] = __uint_as_float(v.x << 16);
  f[1] = __uint_as_float(v.x & 0xffff0000u);
  f[2] = __uint_as_float(v.y << 16);
  f[3] = __uint_as_float(v.y & 0xffff0000u);
  f[4] = __uint_as_float(v.z << 16);
  f[5] = __uint_as_float(v.z & 0xffff0000u);
  f[6] = __uint_as_float(v.w << 16);
  f[7] = __uint_as_float(v.w & 0xffff0000u);
}

// ---------------- setup kernels ----------------

__global__ __launch_bounds__(THREADS) void init_kernel(int* cnt, int n) {
  int i = blockIdx.x * THREADS + threadIdx.x;
  if (i < n) cnt[i] = 0;
}

__global__ __launch_bounds__(THREADS) void edge_off_kernel(const int* __restrict__ ei,
                                                           int* __restrict__ cnt,
                                                           int* __restrict__ local_off, int E) {
  int e = blockIdx.x * THREADS + threadIdx.x;
  if (e >= E) return;
  int d = ei[E + e];
  local_off[e] = atomicAdd(cnt + d, 1);
}

// ---------------- scan: rstart = block-local exclusive; bpre = block prefixes ----------------
// final row start = rstart[i] + bpre[i>>10]  (consumers add)

__global__ __launch_bounds__(256) void scan1_kernel(const int* __restrict__ cnt, int* __restrict__ rstart,
                                                    int* __restrict__ bsum, int n) {
  int t = threadIdx.x;
  int lane = t & 63, wave = t >> 6;
  int base = blockIdx.x * 1024 + t * 4;
  int4 v = make_int4(0, 0, 0, 0);
  if (base + 3 < n) v = *(const int4*)(cnt + base);
  else if (base < n) {
    v.x = cnt[base];
    if (base + 1 < n) v.y = cnt[base + 1];
    if (base + 2 < n) v.z = cnt[base + 2];
  }
  int p1 = v.x, p2 = p1 + v.y, p3 = p2 + v.z, tsum = p3 + v.w;
  int incl = tsum;
#pragma unroll
  for (int off = 1; off < 64; off <<= 1) {
    int u = __shfl_up(incl, off);
    if (lane >= off) incl += u;
  }
  __shared__ int wt[4];
  if (lane == 63) wt[wave] = incl;
  __syncthreads();
  int wadd = 0;
#pragma unroll
  for (int w = 0; w < 4; w++) wadd += (w < wave) ? wt[w] : 0;
  int excl = wadd + incl - tsum;
  if (base < n) {
    rstart[base] = excl;
    if (base + 1 < n) rstart[base + 1] = excl + p1;
    if (base + 2 < n) rstart[base + 2] = excl + p2;
    if (base + 3 < n) rstart[base + 3] = excl + p3;
  }
  if (t == 0) bsum[blockIdx.x] = wt[0] + wt[1] + wt[2] + wt[3];
}

__global__ __launch_bounds__(64) void scan2_kernel(const int* __restrict__ bsum, int* __restrict__ bpre, int nb) {
  int t = threadIdx.x;
  int v = (t < nb) ? bsum[t] : 0;
  int incl = v;
#pragma unroll
  for (int off = 1; off < 64; off <<= 1) {
    int u = __shfl_up(incl, off);
    if (t >= off) incl += u;
  }
  if (t < nb) bpre[t] = incl - v;
}

__device__ __forceinline__ int row_start(const int* rstart, const int* bpre, int i) {
  return rstart[i] + bpre[i >> 10];
}

// ---------------- CSR build ----------------

__global__ __launch_bounds__(THREADS) void csr_build_kernel(const int* __restrict__ ei, const float* __restrict__ ew,
                                                            const int* __restrict__ rstart, const int* __restrict__ bpre,
                                                            const int* __restrict__ local_off,
                                                            int2* __restrict__ csr, int E) {
  int e = blockIdx.x * THREADS + threadIdx.x;
  if (e >= E) return;
  int s = ei[e];
  int d = ei[E + e];
  int pos = row_start(rstart, bpre, d) + local_off[e];
  csr[pos] = make_int2(s, __float_as_int(ew[e]));
}

__global__ __launch_bounds__(256) void deg_wave_kernel(const int2* __restrict__ csr,
                                                       const int* __restrict__ rstart, const int* __restrict__ bpre,
                                                       const int* __restrict__ cnt,
                                                       float* __restrict__ dinv, int nnodes) {
  int wave = threadIdx.x >> 6, lane = threadIdx.x & 63;
  int node = blockIdx.x * 4 + wave;
  if (node >= nnodes) return;
  int rs = row_start(rstart, bpre, node), c = cnt[node];
  float s = 0.f;
  for (int i = lane; i < c; i += 64) s += __int_as_float(csr[rs + i].y);
#pragma unroll
  for (int m = 32; m; m >>= 1) s += __shfl_xor(s, m);
  if (lane == 0) dinv[node] = rsqrtf(1.0f + s);
}

__global__ __launch_bounds__(256) void norm_wave_kernel(int2* __restrict__ csr,
                                                        const int* __restrict__ rstart, const int* __restrict__ bpre,
                                                        const int* __restrict__ cnt,
                                                        const float* __restrict__ dinv, int nnodes) {
  int wave = threadIdx.x >> 6, lane = threadIdx.x & 63;
  int node = blockIdx.x * 4 + wave;
  if (node >= nnodes) return;
  int rs = row_start(rstart, bpre, node), c = cnt[node];
  float dd = dinv[node];
  for (int i = lane; i < c; i += 64) {
    int2 en = csr[rs + i];
    float w = __int_as_float(en.y);
    csr[rs + i].y = __float_as_int(dinv[en.x] * w * dd);
  }
}

// ---------------- bf16 cast of x ----------------

__global__ __launch_bounds__(256) void cast_bf16_kernel(const float* __restrict__ in,
                                                        unsigned short* __restrict__ out, int n8) {
  int t = blockIdx.x * 256 + threadIdx.x;
  if (t >= n8) return;
  const float* p = in + (size_t)t * 8;
  float4 a = *(const float4*)p;
  float4 b = *(const float4*)(p + 4);
  ushort4 o0, o1;
  o0.x = f2bf_rne(a.x); o0.y = f2bf_rne(a.y); o0.z = f2bf_rne(a.z); o0.w = f2bf_rne(a.w);
  o1.x = f2bf_rne(b.x); o1.y = f2bf_rne(b.y); o1.z = f2bf_rne(b.z); o1.w = f2bf_rne(b.w);
  *(ushort4*)(out + (size_t)t * 8) = o0;
  *(ushort4*)(out + (size_t)t * 8 + 4) = o1;
}

// ---------------- W split: transpose + hi/lo bf16 decomposition ----------------

__global__ __launch_bounds__(256) void wsplit_kernel(const float* __restrict__ W1, const float* __restrict__ Wl,
                                                     const float* __restrict__ Ws, const float* __restrict__ W2,
                                                     unsigned short* __restrict__ whi, unsigned short* __restrict__ wlo) {
  int idx = blockIdx.x * 256 + threadIdx.x;
  if (idx >= 448 * 128) return;
  int slot = idx >> 7;
  int k = idx & 127;
  const float* W; int n, ncols;
  if (slot < 128)      { W = W1; n = slot;       ncols = 128; }
  else if (slot < 192) { W = Wl; n = slot - 128; ncols = 64;  }
  else if (slot < 320) { W = Ws; n = slot - 192; ncols = 128; }
  else                 { W = W2; n = slot - 320; ncols = 128; }
  float v = W[(size_t)k * ncols + n];
  unsigned short hi = f2bf_rne(v);
  float hif = __uint_as_float((uint32)hi << 16);
  unsigned short lo = f2bf_rne(v - hif);
  whi[idx] = hi;
  wlo[idx] = lo;
}

// ---------------- MFMA GEMM v3: B-fragments resident in registers ----------------

struct Chunk {
  const unsigned short* whi;
  const unsigned short* wlo;
  const float* bias;
  void* out;
  int ostride;
  int obf16;
};
struct GemmArgs { Chunk c[5]; };

__global__ __launch_bounds__(256, 2) void gemm_v3(const unsigned short* __restrict__ A,
                                                  GemmArgs args, int M, int nTiles) {
  Chunk d = args.c[blockIdx.x];
  int w = threadIdx.x >> 6, lane = threadIdx.x & 63;
  int n16 = lane & 15, quad = lane >> 4;

  bf16x8 Bh[4][4], Bl[4][4];
  {
    const unsigned short* wh = d.whi + (size_t)n16 * 128 + quad * 8;
    const unsigned short* wl = d.wlo + (size_t)n16 * 128 + quad * 8;
#pragma unroll
    for (int ct = 0; ct < 4; ct++)
#pragma unroll
      for (int ks = 0; ks < 4; ks++) {
        Bh[ct][ks] = *(const bf16x8*)(wh + ct * 16 * 128 + ks * 32);
        Bl[ct][ks] = *(const bf16x8*)(wl + ct * 16 * 128 + ks * 32);
      }
  }
  float bv[4];
#pragma unroll
  for (int ct = 0; ct < 4; ct++) bv[ct] = d.bias ? d.bias[ct * 16 + n16] : 0.f;

  for (int tile = blockIdx.y; tile < nTiles; tile += gridDim.y) {
    int bm = tile * 128;
    int r0 = bm + w * 32 + n16;
    int r1 = r0 + 16;
    int r0c = r0 < M ? r0 : M - 1;
    int r1c = r1 < M ? r1 : M - 1;
    const unsigned short* a0 = A + (size_t)r0c * 128 + quad * 8;
    const unsigned short* a1 = A + (size_t)r1c * 128 + quad * 8;
    bf16x8 av0[4], av1[4];
#pragma unroll
    for (int ks = 0; ks < 4; ks++) {
      av0[ks] = *(const bf16x8*)(a0 + ks * 32);
      av1[ks] = *(const bf16x8*)(a1 + ks * 32);
    }

    f32x4 acc[2][4];
#pragma unroll
    for (int rt = 0; rt < 2; rt++)
#pragma unroll
      for (int ct = 0; ct < 4; ct++) acc[rt][ct] = (f32x4){0.f, 0.f, 0.f, 0.f};

#pragma unroll
    for (int ks = 0; ks < 4; ks++)
#pragma unroll
      for (int ct = 0; ct < 4; ct++) {
        acc[0][ct] = __builtin_amdgcn_mfma_f32_16x16x32_bf16(av0[ks], Bh[ct][ks], acc[0][ct], 0, 0, 0);
        acc[0][ct] = __builtin_amdgcn_mfma_f32_16x16x32_bf16(av0[ks], Bl[ct][ks], acc[0][ct], 0, 0, 0);
        acc[1][ct] = __builtin_amdgcn_mfma_f32_16x16x32_bf16(av1[ks], Bh[ct][ks], acc[1][ct], 0, 0, 0);
        acc[1][ct] = __builtin_amdgcn_mfma_f32_16x16x32_bf16(av1[ks], Bl[ct][ks], acc[1][ct], 0, 0, 0);
      }

#pragma unroll
    for (int ct = 0; ct < 4; ct++) {
      int col = ct * 16 + n16;
#pragma unroll
      for (int rt = 0; rt < 2; rt++) {
#pragma unroll
        for (int reg = 0; reg < 4; reg++) {
          int row = bm + w * 32 + rt * 16 + quad * 4 + reg;
          if (row < M) {
            float v = acc[rt][ct][reg] + bv[ct];
            if (d.obf16)
              ((unsigned short*)d.out)[(size_t)row * d.ostride + col] = f2bf_rne(v);
            else
              ((float*)d.out)[(size_t)row * d.ostride + col] = v;
          }
        }
      }
    }
  }
}

// ---------------- fused: leader score + conv1 + gating, wave per node ----------------
// phase A: agg64 over hl -> leader (all lanes); phase B: agg128 over h1 -> gate -> bf16 h_new

__global__ __launch_bounds__(256) void agg_conv1_fused(const unsigned short* __restrict__ h1,
                                                       const unsigned short* __restrict__ hl,
                                                       const int* __restrict__ rstart, const int* __restrict__ bpre,
                                                       const int* __restrict__ cnt,
                                                       const int2* __restrict__ csr,
                                                       const float* __restrict__ dinv,
                                                       const float* __restrict__ b1, const float* __restrict__ bl,
                                                       const float* __restrict__ Wl2, const float* __restrict__ bl2,
                                                       const float* __restrict__ hself,
                                                       unsigned short* __restrict__ hnew_out,
                                                       float* __restrict__ leader_out, int nnodes) {
  int wave = threadIdx.x >> 6;
  int lane = threadIdx.x & 63;
  int node = blockIdx.x * 4 + wave;
  if (node >= nnodes) return;
  int rs = row_start(rstart, bpre, node);
  int n = cnt[node];
  float di = dinv[node];
  float dsq = di * di;

  // ---- phase A: leader (64-wide, 8 edges in flight, unroll 2) ----
  float l;
  {
    int g = lane >> 3, q = lane & 7;
    float acc[8] = {};
    if (g == 0) {
      uint4 v = *(const uint4*)(hl + (size_t)node * 64 + 8 * q);
      float f[8]; unpack8(v, f);
#pragma unroll
      for (int j = 0; j < 8; j++) acc[j] = dsq * f[j];
    }
    int e = g;
    for (; e + 8 < n; e += 16) {
      int2 en0 = csr[rs + e];
      int2 en1 = csr[rs + e + 8];
      uint4 v0 = *(const uint4*)(hl + (size_t)en0.x * 64 + 8 * q);
      uint4 v1 = *(const uint4*)(hl + (size_t)en1.x * 64 + 8 * q);
      float nrm0 = __int_as_float(en0.y), nrm1 = __int_as_float(en1.y);
      float f0[8], f1[8]; unpack8(v0, f0); unpack8(v1, f1);
#pragma unroll
      for (int j = 0; j < 8; j++) acc[j] += nrm0 * f0[j] + nrm1 * f1[j];
    }
    if (e < n) {
      int2 en = csr[rs + e];
      uint4 v = *(const uint4*)(hl + (size_t)en.x * 64 + 8 * q);
      float nrm = __int_as_float(en.y);
      float f[8]; unpack8(v, f);
#pragma unroll
      for (int j = 0; j < 8; j++) acc[j] += nrm * f[j];
    }
#pragma unroll
    for (int j = 0; j < 8; j++) {
      acc[j] += __shfl_xor(acc[j], 8);
      acc[j] += __shfl_xor(acc[j], 16);
      acc[j] += __shfl_xor(acc[j], 32);
    }
    float b[8], w2[8];
    *(float4*)&b[0] = *(const float4*)(bl + 8 * q);
    *(float4*)&b[4] = *(const float4*)(bl + 8 * q + 4);
    *(float4*)&w2[0] = *(const float4*)(Wl2 + 8 * q);
    *(float4*)&w2[4] = *(const float4*)(Wl2 + 8 * q + 4);
    float part = 0.f;
#pragma unroll
    for (int j = 0; j < 8; j++) part += fmaxf(acc[j] + b[j], 0.f) * w2[j];
    part += __shfl_xor(part, 1);
    part += __shfl_xor(part, 2);
    part += __shfl_xor(part, 4);
    float z = part + bl2[0];
    l = 1.f / (1.f + expf(-z));
    if (lane == 0) leader_out[node] = l;
  }

  // ---- phase B: conv1 (128-wide, 4 groups, unroll 2) + gate ----
  {
    int g = lane >> 4, q = lane & 15;
    float acc[8] = {};
    if (g == 0) {
      uint4 v = *(const uint4*)(h1 + (size_t)node * 128 + 8 * q);
      float f[8]; unpack8(v, f);
#pragma unroll
      for (int j = 0; j < 8; j++) acc[j] = dsq * f[j];
    }
    int e = g;
    for (; e + 4 < n; e += 8) {
      int2 en0 = csr[rs + e];
      int2 en1 = csr[rs + e + 4];
      uint4 v0 = *(const uint4*)(h1 + (size_t)en0.x * 128 + 8 * q);
      uint4 v1 = *(const uint4*)(h1 + (size_t)en1.x * 128 + 8 * q);
      float nrm0 = __int_as_float(en0.y), nrm1 = __int_as_float(en1.y);
      float f0[8], f1[8]; unpack8(v0, f0); unpack8(v1, f1);
#pragma unroll
      for (int j = 0; j < 8; j++) acc[j] += nrm0 * f0[j] + nrm1 * f1[j];
    }
    if (e < n) {
      int2 en = csr[rs + e];
      uint4 v = *(const uint4*)(h1 + (size_t)en.x * 128 + 8 * q);
      float nrm = __int_as_float(en.y);
      float f[8]; unpack8(v, f);
#pragma unroll
      for (int j = 0; j < 8; j++) acc[j] += nrm * f[j];
    }
#pragma unroll
    for (int j = 0; j < 8; j++) {
      acc[j] += __shfl_xor(acc[j], 16);
      acc[j] += __shfl_xor(acc[j], 32);
    }
    if (g == 0) {
      float b[8], r[8], hs[8];
      *(float4*)&b[0] = *(const float4*)(b1 + 8 * q);
      *(float4*)&b[4] = *(const float4*)(b1 + 8 * q + 4);
      *(float4*)&hs[0] = *(const float4*)(hself + (size_t)node * 128 + 8 * q);
      *(float4*)&hs[4] = *(const float4*)(hself + (size_t)node * 128 + 8 * q + 4);
#pragma unroll
      for (int j = 0; j < 8; j++) {
        r[j] = fmaxf(acc[j] + b[j], 0.f);
        r[j] = (1.f - l) * r[j] + l * hs[j];
      }
      ushort4 p0, p1;
      p0.x = f2bf_rne(r[0]); p0.y = f2bf_rne(r[1]); p0.z = f2bf_rne(r[2]); p0.w = f2bf_rne(r[3]);
      p1.x = f2bf_rne(r[4]); p1.y = f2bf_rne(r[5]); p1.z = f2bf_rne(r[6]); p1.w = f2bf_rne(r[7]);
      *(ushort4*)(hnew_out + (size_t)node * 128 + 8 * q) = p0;
      *(ushort4*)(hnew_out + (size_t)node * 128 + 8 * q + 4) = p1;
    }
  }
}

// ---------------- conv2: 128-wide bf16 gather, relu, fp32 out (unroll 2) ----------------

__global__ __launch_bounds__(256) void agg_conv2_kernel(const unsigned short* __restrict__ h,
                                                        const int* __restrict__ rstart, const int* __restrict__ bpre,
                                                        const int* __restrict__ cnt,
                                                        const int2* __restrict__ csr,
                                                        const float* __restrict__ dinv, const float* __restrict__ bias,
                                                        float* __restrict__ out, int nnodes) {
  int wave = threadIdx.x >> 6;
  int lane = threadIdx.x & 63;
  int node = blockIdx.x * 4 + wave;
  if (node >= nnodes) return;
  int g = lane >> 4;
  int q = lane & 15;
  int rs = row_start(rstart, bpre, node);
  int n = cnt[node];

  float acc[8] = {};
  if (g == 0) {
    float s = dinv[node]; s *= s;
    uint4 v = *(const uint4*)(h + (size_t)node * 128 + 8 * q);
    float f[8]; unpack8(v, f);
#pragma unroll
    for (int j = 0; j < 8; j++) acc[j] = s * f[j];
  }
  int e = g;
  for (; e + 4 < n; e += 8) {
    int2 en0 = csr[rs + e];
    int2 en1 = csr[rs + e + 4];
    uint4 v0 = *(const uint4*)(h + (size_t)en0.x * 128 + 8 * q);
    uint4 v1 = *(const uint4*)(h + (size_t)en1.x * 128 + 8 * q);
    float nrm0 = __int_as_float(en0.y), nrm1 = __int_as_float(en1.y);
    float f0[8], f1[8]; unpack8(v0, f0); unpack8(v1, f1);
#pragma unroll
    for (int j = 0; j < 8; j++) acc[j] += nrm0 * f0[j] + nrm1 * f1[j];
  }
  if (e < n) {
    int2 en = csr[rs + e];
    uint4 v = *(const uint4*)(h + (size_t)en.x * 128 + 8 * q);
    float nrm = __int_as_float(en.y);
    float f[8]; unpack8(v, f);
#pragma unroll
    for (int j = 0; j < 8; j++) acc[j] += nrm * f[j];
  }
#pragma unroll
  for (int j = 0; j < 8; j++) {
    acc[j] += __shfl_xor(acc[j], 16);
    acc[j] += __shfl_xor(acc[j], 32);
  }
  if (g == 0) {
    float b[8], r[8];
    *(float4*)&b[0] = *(const float4*)(bias + 8 * q);
    *(float4*)&b[4] = *(const float4*)(bias + 8 * q + 4);
#pragma unroll
    for (int j = 0; j < 8; j++) r[j] = fmaxf(acc[j] + b[j], 0.f);
    *(float4*)(out + (size_t)node * 128 + 8 * q) = *(float4*)&r[0];
    *(float4*)(out + (size_t)node * 128 + 8 * q + 4) = *(float4*)&r[4];
  }
}

// ---------------- host ----------------

extern "C" void kernel_launch(void* const* d_in, const int* in_sizes, int n_in,
                              void* d_out, int out_size, void* d_ws, size_t ws_size,
                              hipStream_t stream) {
  const float* x   = (const float*)d_in[0];
  const int*   ei  = (const int*)d_in[1];
  const float* ew  = (const float*)d_in[2];
  const float* W1  = (const float*)d_in[3];
  const float* b1  = (const float*)d_in[4];
  const float* W2  = (const float*)d_in[5];
  const float* b2  = (const float*)d_in[6];
  const float* Wsp = (const float*)d_in[7];
  const float* bs  = (const float*)d_in[8];
  const float* Wl  = (const float*)d_in[9];
  const float* bl  = (const float*)d_in[10];
  const float* Wl2 = (const float*)d_in[11];
  const float* bl2 = (const float*)d_in[12];

  const int N = in_sizes[0] / 128;   // 50000
  const int E = in_sizes[1] / 2;     // 800000

  char* ws = (char*)d_ws;
  size_t off = 0;
  auto alloc = [&](size_t bytes) -> void* {
    void* p = ws + off;
    off = (off + bytes + 255) & ~(size_t)255;
    return p;
  };
  float* dinv      = (float*)alloc((size_t)N * 4);
  int*   cnt       = (int*)alloc((size_t)N * 4);
  int*   rstart    = (int*)alloc((size_t)N * 4);
  int*   local_off = (int*)alloc((size_t)E * 4);
  int2*  csr       = (int2*)alloc((size_t)E * 8);
  unsigned short* xbf    = (unsigned short*)alloc((size_t)N * 128 * 2);
  unsigned short* h1bf   = (unsigned short*)alloc((size_t)N * 128 * 2);  // h1, then h2
  unsigned short* hlbf   = (unsigned short*)alloc((size_t)N * 64 * 2);
  unsigned short* hnewbf = (unsigned short*)alloc((size_t)N * 128 * 2);
  float* bufC      = (float*)alloc((size_t)N * 128 * 4);  // h_self_proj (fp32)
  unsigned short* whi = (unsigned short*)alloc((size_t)448 * 128 * 2);
  unsigned short* wlo = (unsigned short*)alloc((size_t)448 * 128 * 2);
  int*   bsum      = (int*)alloc(256 * 4);
  int*   bpre      = (int*)alloc(256 * 4);

  float* h_final = (float*)d_out;
  float* leader  = (float*)d_out + (size_t)N * 128;

  int gN = (N + THREADS - 1) / THREADS;
  int gE = (E + THREADS - 1) / THREADS;
  int nScanBlocks = (N + 1023) / 1024;   // 49 <= 64
  int gWave = (N + 3) / 4;
  int nTiles = (N + 127) / 128;          // 391

  // graph prep — exactly one atomic per edge
  init_kernel<<<gN, THREADS, 0, stream>>>(cnt, N);
  edge_off_kernel<<<gE, THREADS, 0, stream>>>(ei, cnt, local_off, E);
  scan1_kernel<<<nScanBlocks, 256, 0, stream>>>(cnt, rstart, bsum, N);
  scan2_kernel<<<1, 64, 0, stream>>>(bsum, bpre, nScanBlocks);
  csr_build_kernel<<<gE, THREADS, 0, stream>>>(ei, ew, rstart, bpre, local_off, csr, E);
  deg_wave_kernel<<<gWave, 256, 0, stream>>>(csr, rstart, bpre, cnt, dinv, N);
  norm_wave_kernel<<<gWave, 256, 0, stream>>>(csr, rstart, bpre, cnt, dinv, N);

  // weight split + x cast
  wsplit_kernel<<<(448 * 128 + 255) / 256, 256, 0, stream>>>(W1, Wl, Wsp, W2, whi, wlo);
  cast_bf16_kernel<<<(N * 16 + 255) / 256, 256, 0, stream>>>(x, xbf, N * 16);

  // fused x-GEMMs: h1 = x@W1 (bf16), hl = x@Wl (bf16), hsp = x@Ws + bs (fp32)
  {
    GemmArgs ga;
    ga.c[0] = {whi + 0 * 128,   wlo + 0 * 128,   nullptr, h1bf,      128, 1};
    ga.c[1] = {whi + 64 * 128,  wlo + 64 * 128,  nullptr, h1bf + 64, 128, 1};
    ga.c[2] = {whi + 128 * 128, wlo + 128 * 128, nullptr, hlbf,      64,  1};
    ga.c[3] = {whi + 192 * 128, wlo + 192 * 128, bs,      bufC,      128, 0};
    ga.c[4] = {whi + 256 * 128, wlo + 256 * 128, bs + 64, bufC + 64, 128, 0};
    gemm_v3<<<dim3(5, 104), 256, 0, stream>>>(xbf, ga, N, nTiles);
  }

  // leader + conv1 + gating fused -> h_new (bf16) + leader (fp32 out)
  agg_conv1_fused<<<gWave, 256, 0, stream>>>(h1bf, hlbf, rstart, bpre, cnt, csr, dinv,
                                             b1, bl, Wl2, bl2, bufC, hnewbf, leader, N);

  // h2 = h_new @ W2 (bf16 out, reuse h1bf)
  {
    GemmArgs ga;
    ga.c[0] = {whi + 320 * 128, wlo + 320 * 128, nullptr, h1bf,      128, 1};
    ga.c[1] = {whi + 384 * 128, wlo + 384 * 128, nullptr, h1bf + 64, 128, 1};
    ga.c[2] = ga.c[0]; ga.c[3] = ga.c[0]; ga.c[4] = ga.c[0];
    gemm_v3<<<dim3(2, 256), 256, 0, stream>>>(hnewbf, ga, N, nTiles);
  }
  // conv2 + relu -> h_final (fp32)
  agg_conv2_kernel<<<gWave, 256, 0, stream>>>(h1bf, rstart, bpre, cnt, csr,
                                              dinv, b2, h_final, N);
}